// Round 7
// baseline (448.119 us; speedup 1.0000x reference)
//
#include <hip/hip_runtime.h>
#include <cstddef>

#define DD 128
#define TILE_R 128
#define GBLK 512
#define AS_LD 132
#define SCAN_CHUNK 2048   // 1024 threads x 2 elements
#define PART_ELEMS 4096   // elements per partition block (256 thr x 16)
#define MAXB 128          // max destination-range buckets

__device__ __forceinline__ float4 f4add(const float4& a, const float4& b) {
    return make_float4(a.x + b.x, a.y + b.y, a.z + b.z, a.w + b.w);
}
__device__ __forceinline__ float4 f4scale(const float4& a, float s) {
    return make_float4(a.x * s, a.y * s, a.z * s, a.w * s);
}
__device__ __forceinline__ float4 f4relu(const float4& a) {
    return make_float4(fmaxf(a.x, 0.f), fmaxf(a.y, 0.f), fmaxf(a.z, 0.f), fmaxf(a.w, 0.f));
}
__device__ __forceinline__ void f4fma(float a, const float4& b, float4& c) {
    c.x = fmaf(a, b.x, c.x);
    c.y = fmaf(a, b.y, c.y);
    c.z = fmaf(a, b.z, c.z);
    c.w = fmaf(a, b.w, c.w);
}
// pack two f32 -> one u32 of 2 bf16 (RNE)
__device__ __forceinline__ unsigned bf16pk(float x, float y) {
    unsigned a = __float_as_uint(x);
    unsigned b = __float_as_uint(y);
    a = (a + 0x7FFFu + ((a >> 16) & 1u)) >> 16;
    b = (b + 0x7FFFu + ((b >> 16) & 1u)) >> 16;
    return a | (b << 16);
}
__device__ __forceinline__ float bflo(unsigned u) { return __uint_as_float(u << 16); }
__device__ __forceinline__ float bfhi(unsigned u) { return __uint_as_float(u & 0xFFFF0000u); }

// bijective XCD-chunked block swizzle (m204 variant): XCD k gets a contiguous chunk
__device__ __forceinline__ int xcd_swz(int orig, int nwg) {
    int q = nwg >> 3, r = nwg & 7;
    int x = orig & 7, i = orig >> 3;
    return (x < r ? x * (q + 1) : r * (q + 1) + (x - r) * q) + i;
}

// ---------------------------------------------------------------------------
// histogram: count incidences per edge and per vertex (one pass over M)
__global__ void hist_kernel(const int* __restrict__ eidx, const int* __restrict__ vidx,
                            int* __restrict__ e_cnt, int* __restrict__ v_cnt, int M)
{
    int m = blockIdx.x * blockDim.x + threadIdx.x;
    if (m >= M) return;
    atomicAdd(&e_cnt[eidx[m]], 1);
    atomicAdd(&v_cnt[vidx[m]], 1);
}

// ---------------------------------------------------------------------------
// multi-block exclusive scan, phase 1: per-block (2048-elem chunk) sums
__global__ __launch_bounds__(1024)
void scan_reduce_kernel(const int* __restrict__ cnt, int* __restrict__ partial, int n)
{
    __shared__ int sdata[1024];
    int base = blockIdx.x * SCAN_CHUNK;
    int t = threadIdx.x;
    int i0 = base + 2 * t;
    int a = (i0 < n)     ? cnt[i0]     : 0;
    int b = (i0 + 1 < n) ? cnt[i0 + 1] : 0;
    sdata[t] = a + b;
    __syncthreads();
    for (int off = 512; off > 0; off >>= 1) {
        if (t < off) sdata[t] += sdata[t + off];
        __syncthreads();
    }
    if (t == 0) partial[blockIdx.x] = sdata[0];
}

// phase 2: exclusive scan of partials (nb <= 1024) in one block; also writes total -> start[n]
__global__ __launch_bounds__(1024)
void scan_partials_kernel(int* __restrict__ partial, int nb, int* __restrict__ start, int n)
{
    __shared__ int sdata[1024];
    int t = threadIdx.x;
    int v = (t < nb) ? partial[t] : 0;
    sdata[t] = v;
    __syncthreads();
    int x = v;
    for (int off = 1; off < 1024; off <<= 1) {
        int y = (t >= off) ? sdata[t - off] : 0;
        __syncthreads();
        x += y;
        sdata[t] = x;
        __syncthreads();
    }
    if (t < nb) partial[t] = x - v;        // exclusive
    if (t == nb - 1) start[n] = x;         // grand total
}

// phase 3: per-chunk scan + chunk base -> exclusive start[]
__global__ __launch_bounds__(1024)
void scan_write_kernel(const int* __restrict__ cnt, const int* __restrict__ partial,
                       int* __restrict__ start, int n)
{
    __shared__ int sdata[1024];
    int base = blockIdx.x * SCAN_CHUNK;
    int t = threadIdx.x;
    int i0 = base + 2 * t;
    int a = (i0 < n)     ? cnt[i0]     : 0;
    int b = (i0 + 1 < n) ? cnt[i0 + 1] : 0;
    int s = a + b;
    sdata[t] = s;
    __syncthreads();
    int x = s;
    for (int off = 1; off < 1024; off <<= 1) {
        int y = (t >= off) ? sdata[t - off] : 0;
        __syncthreads();
        x += y;
        sdata[t] = x;
        __syncthreads();
    }
    int ex = partial[blockIdx.x] + x - s;  // exclusive prefix before element i0
    if (i0 < n)     start[i0]     = ex;
    if (i0 + 1 < n) start[i0 + 1] = ex + a;
}

// ---------------------------------------------------------------------------
// bucket cursor init: bcur[b] = rstart[min(b<<shift, n)]
__global__ void bucket_init_kernel(const int* __restrict__ rstart, int n, int shift,
                                   int nb, int* __restrict__ bcur)
{
    int b = threadIdx.x;
    if (b >= nb) return;
    long long i = (long long)b << shift;
    if (i > n) i = n;
    bcur[b] = rstart[i];
}

// ---------------------------------------------------------------------------
// partition pass A: LDS-staged bucket binning. Each block counts its 4096
// elements into <=128 LDS counters, reserves per-bucket ranges with ONE global
// atomic per (block,bucket), then writes {d|w<<17, src} records bucket-grouped.
__global__ __launch_bounds__(256)
void part_kernel(const int* __restrict__ didx, const int* __restrict__ sidx,
                 const float* __restrict__ w, int* __restrict__ bcur,
                 int2* __restrict__ tmp, int M, int shift, int nb)
{
    __shared__ int lcnt[MAXB];
    __shared__ int lbase[MAXB];
    const int t = threadIdx.x;
    const int base = blockIdx.x * PART_ELEMS;
    const int end = min(base + PART_ELEMS, M);

    for (int i = t; i < nb; i += 256) lcnt[i] = 0;
    __syncthreads();
    for (int j = base + t; j < end; j += 256)
        atomicAdd(&lcnt[didx[j] >> shift], 1);
    __syncthreads();
    for (int i = t; i < nb; i += 256) {
        int c = lcnt[i];
        lbase[i] = c ? atomicAdd(&bcur[i], c) : 0;
        lcnt[i] = 0;
    }
    __syncthreads();
    for (int j = base + t; j < end; j += 256) {
        int d = didx[j];
        int b = d >> shift;
        int pos = lbase[b] + atomicAdd(&lcnt[b], 1);
        int wq = (int)(w[j] * 32767.0f + 0.5f);
        wq = wq < 32767 ? wq : 32767;
        tmp[pos] = make_int2(d | (wq << 17), sidx[j]);
    }
}

// partition pass B: stream bucket-grouped records (XCD-chunked swizzle keeps each
// XCD in a contiguous bucket range -> pack writes hit an L2-resident window).
// Consumes cnt via atomicSub. pack[p] = src | (w15 << 17).
__global__ __launch_bounds__(256)
void place_kernel(const int2* __restrict__ tmp, const int* __restrict__ rstart,
                  int* __restrict__ rcnt, unsigned* __restrict__ pack, int M, int nwg)
{
    int blk = xcd_swz(blockIdx.x, nwg);
    int j = blk * 256 + threadIdx.x;
    if (j >= M) return;
    int2 r = tmp[j];
    int d = r.x & 0x1FFFF;
    int p = rstart[d] + atomicSub(&rcnt[d], 1) - 1;
    pack[p] = (unsigned)r.y | (((unsigned)r.x >> 17) << 17);
}

// ---------------------------------------------------------------------------
// GEMM1: vw(bf16) = relu(v @ W + b_v) * v_weight
__global__ __launch_bounds__(GBLK, 1)
void gemm_v2e_kernel(const float* __restrict__ v, const float* __restrict__ W,
                     const float* __restrict__ bv, const float* __restrict__ vweight,
                     unsigned* __restrict__ vwb, int nrows)
{
    __shared__ float Ws[DD * DD];
    __shared__ float As[TILE_R * AS_LD];

    const int t = threadIdx.x;
    const int row0 = blockIdx.x * TILE_R;

    #pragma unroll
    for (int i = 0; i < 8; ++i) {
        int p = t + GBLK * i;
        *reinterpret_cast<float4*>(&Ws[p * 4]) = *reinterpret_cast<const float4*>(&W[p * 4]);
    }
    #pragma unroll
    for (int i = 0; i < 8; ++i) {
        int p  = t + GBLK * i;
        int r  = p >> 5;
        int c4 = p & 31;
        int gr = row0 + r;
        float4 val = make_float4(0.f, 0.f, 0.f, 0.f);
        if (gr < nrows) val = *reinterpret_cast<const float4*>(&v[(size_t)gr * DD + c4 * 4]);
        *reinterpret_cast<float4*>(&As[r * AS_LD + c4 * 4]) = val;
    }
    __syncthreads();

    const int rg = t >> 4;
    const int cg = t & 15;
    const int r0 = rg * 4;
    const int c0 = cg * 4;
    const int c1 = 64 + cg * 4;

    float4 acc0[4], acc1[4];
    #pragma unroll
    for (int i = 0; i < 4; ++i) {
        acc0[i] = make_float4(0.f, 0.f, 0.f, 0.f);
        acc1[i] = make_float4(0.f, 0.f, 0.f, 0.f);
    }

    #pragma unroll 4
    for (int k = 0; k < DD; ++k) {
        float4 b0 = *reinterpret_cast<const float4*>(&Ws[k * DD + c0]);
        float4 b1 = *reinterpret_cast<const float4*>(&Ws[k * DD + c1]);
        #pragma unroll
        for (int i = 0; i < 4; ++i) {
            float a = As[(r0 + i) * AS_LD + k];
            f4fma(a, b0, acc0[i]);
            f4fma(a, b1, acc1[i]);
        }
    }

    float4 bv0 = *reinterpret_cast<const float4*>(&bv[c0]);
    float4 bv1 = *reinterpret_cast<const float4*>(&bv[c1]);

    #pragma unroll
    for (int i = 0; i < 4; ++i) {
        int gr = row0 + r0 + i;
        if (gr >= nrows) break;
        float wt = vweight[gr];
        float4 o0 = f4scale(f4relu(f4add(acc0[i], bv0)), wt);
        float4 o1 = f4scale(f4relu(f4add(acc1[i], bv1)), wt);
        uint2 p0 = make_uint2(bf16pk(o0.x, o0.y), bf16pk(o0.z, o0.w));
        uint2 p1 = make_uint2(bf16pk(o1.x, o1.y), bf16pk(o1.z, o1.w));
        *reinterpret_cast<uint2*>(&vwb[(size_t)gr * 64 + cg * 2])      = p0;
        *reinterpret_cast<uint2*>(&vwb[(size_t)gr * 64 + 32 + cg * 2]) = p1;
    }
}

// ---------------------------------------------------------------------------
// GEMM2: ev(bf16) = relu(e_out @ W + b_e) / 3   (e_out already final, f32)
__global__ __launch_bounds__(GBLK, 1)
void gemm_e2v_kernel(const float* __restrict__ eout, const float* __restrict__ W,
                     const float* __restrict__ be, unsigned* __restrict__ evb, int nrows)
{
    __shared__ float Ws[DD * DD];
    __shared__ float As[TILE_R * AS_LD];

    const int t = threadIdx.x;
    const int row0 = blockIdx.x * TILE_R;

    #pragma unroll
    for (int i = 0; i < 8; ++i) {
        int p = t + GBLK * i;
        *reinterpret_cast<float4*>(&Ws[p * 4]) = *reinterpret_cast<const float4*>(&W[p * 4]);
    }
    #pragma unroll
    for (int i = 0; i < 8; ++i) {
        int p  = t + GBLK * i;
        int r  = p >> 5;
        int c4 = p & 31;
        int gr = row0 + r;
        float4 val = make_float4(0.f, 0.f, 0.f, 0.f);
        if (gr < nrows) val = *reinterpret_cast<const float4*>(&eout[(size_t)gr * DD + c4 * 4]);
        *reinterpret_cast<float4*>(&As[r * AS_LD + c4 * 4]) = val;
    }
    __syncthreads();

    const int rg = t >> 4;
    const int cg = t & 15;
    const int r0 = rg * 4;
    const int c0 = cg * 4;
    const int c1 = 64 + cg * 4;

    float4 acc0[4], acc1[4];
    #pragma unroll
    for (int i = 0; i < 4; ++i) {
        acc0[i] = make_float4(0.f, 0.f, 0.f, 0.f);
        acc1[i] = make_float4(0.f, 0.f, 0.f, 0.f);
    }

    #pragma unroll 4
    for (int k = 0; k < DD; ++k) {
        float4 b0 = *reinterpret_cast<const float4*>(&Ws[k * DD + c0]);
        float4 b1 = *reinterpret_cast<const float4*>(&Ws[k * DD + c1]);
        #pragma unroll
        for (int i = 0; i < 4; ++i) {
            float a = As[(r0 + i) * AS_LD + k];
            f4fma(a, b0, acc0[i]);
            f4fma(a, b1, acc1[i]);
        }
    }

    float4 be0 = *reinterpret_cast<const float4*>(&be[c0]);
    float4 be1 = *reinterpret_cast<const float4*>(&be[c1]);
    const float third = 1.0f / 3.0f;

    #pragma unroll
    for (int i = 0; i < 4; ++i) {
        int gr = row0 + r0 + i;
        if (gr >= nrows) break;
        float4 o0 = f4scale(f4relu(f4add(acc0[i], be0)), third);
        float4 o1 = f4scale(f4relu(f4add(acc1[i], be1)), third);
        uint2 p0 = make_uint2(bf16pk(o0.x, o0.y), bf16pk(o0.z, o0.w));
        uint2 p1 = make_uint2(bf16pk(o1.x, o1.y), bf16pk(o1.z, o1.w));
        *reinterpret_cast<uint2*>(&evb[(size_t)gr * 64 + cg * 2])      = p0;
        *reinterpret_cast<uint2*>(&evb[(size_t)gr * 64 + 32 + cg * 2]) = p1;
    }
}

// ---------------------------------------------------------------------------
// e-aggregation with 4x unrolled, MLP-exposed gather loop.
__global__ __launch_bounds__(256)
void e_agg_kernel(const float* __restrict__ e, const unsigned* __restrict__ vwb,
                  const int* __restrict__ start, const unsigned* __restrict__ pack,
                  const float* __restrict__ ers, float* __restrict__ eout, int E)
{
    int row = blockIdx.x * 4 + (threadIdx.x >> 6);
    if (row >= E) return;
    int lane = threadIdx.x & 63;
    int s = start[row], t = start[row + 1];
    float a0 = 0.f, a1 = 0.f, b0 = 0.f, b1 = 0.f, c0 = 0.f, c1 = 0.f, d0 = 0.f, d1 = 0.f;
    int j = s;
    for (; j + 4 <= t; j += 4) {
        unsigned pw0 = pack[j];
        unsigned pw1 = pack[j + 1];
        unsigned pw2 = pack[j + 2];
        unsigned pw3 = pack[j + 3];
        unsigned u0 = vwb[(size_t)(pw0 & 0x1FFFFu) * 64 + lane];
        unsigned u1 = vwb[(size_t)(pw1 & 0x1FFFFu) * 64 + lane];
        unsigned u2 = vwb[(size_t)(pw2 & 0x1FFFFu) * 64 + lane];
        unsigned u3 = vwb[(size_t)(pw3 & 0x1FFFFu) * 64 + lane];
        float w0 = (float)(pw0 >> 17) * (1.0f / 32767.0f);
        float w1 = (float)(pw1 >> 17) * (1.0f / 32767.0f);
        float w2 = (float)(pw2 >> 17) * (1.0f / 32767.0f);
        float w3 = (float)(pw3 >> 17) * (1.0f / 32767.0f);
        a0 = fmaf(bflo(u0), w0, a0); a1 = fmaf(bfhi(u0), w0, a1);
        b0 = fmaf(bflo(u1), w1, b0); b1 = fmaf(bfhi(u1), w1, b1);
        c0 = fmaf(bflo(u2), w2, c0); c1 = fmaf(bfhi(u2), w2, c1);
        d0 = fmaf(bflo(u3), w3, d0); d1 = fmaf(bfhi(u3), w3, d1);
    }
    for (; j < t; ++j) {
        unsigned pw = pack[j];
        float wm = (float)(pw >> 17) * (1.0f / 32767.0f);
        unsigned u = vwb[(size_t)(pw & 0x1FFFFu) * 64 + lane];
        a0 = fmaf(bflo(u), wm, a0); a1 = fmaf(bfhi(u), wm, a1);
    }
    float acc0 = (a0 + b0) + (c0 + d0);
    float acc1 = (a1 + b1) + (c1 + d1);
    float rs = 1.0f / ers[row];
    float2 er = *reinterpret_cast<const float2*>(&e[(size_t)row * DD + lane * 2]);
    float2 o = make_float2((er.x + acc0) * rs, (er.y + acc1) * rs);
    *reinterpret_cast<float2*>(&eout[(size_t)row * DD + lane * 2]) = o;
}

// ---------------------------------------------------------------------------
// v-aggregation, same structure.
__global__ __launch_bounds__(256)
void v_agg_kernel(const float* __restrict__ v, const unsigned* __restrict__ evb,
                  const int* __restrict__ start, const unsigned* __restrict__ pack,
                  const float* __restrict__ vrs, const float* __restrict__ vweight,
                  float* __restrict__ vout, int N)
{
    int row = blockIdx.x * 4 + (threadIdx.x >> 6);
    if (row >= N) return;
    int lane = threadIdx.x & 63;
    int s = start[row], t = start[row + 1];
    float a0 = 0.f, a1 = 0.f, b0 = 0.f, b1 = 0.f, c0 = 0.f, c1 = 0.f, d0 = 0.f, d1 = 0.f;
    int j = s;
    for (; j + 4 <= t; j += 4) {
        unsigned pw0 = pack[j];
        unsigned pw1 = pack[j + 1];
        unsigned pw2 = pack[j + 2];
        unsigned pw3 = pack[j + 3];
        unsigned u0 = evb[(size_t)(pw0 & 0x1FFFFu) * 64 + lane];
        unsigned u1 = evb[(size_t)(pw1 & 0x1FFFFu) * 64 + lane];
        unsigned u2 = evb[(size_t)(pw2 & 0x1FFFFu) * 64 + lane];
        unsigned u3 = evb[(size_t)(pw3 & 0x1FFFFu) * 64 + lane];
        float w0 = (float)(pw0 >> 17) * (1.0f / 32767.0f);
        float w1 = (float)(pw1 >> 17) * (1.0f / 32767.0f);
        float w2 = (float)(pw2 >> 17) * (1.0f / 32767.0f);
        float w3 = (float)(pw3 >> 17) * (1.0f / 32767.0f);
        a0 = fmaf(bflo(u0), w0, a0); a1 = fmaf(bfhi(u0), w0, a1);
        b0 = fmaf(bflo(u1), w1, b0); b1 = fmaf(bfhi(u1), w1, b1);
        c0 = fmaf(bflo(u2), w2, c0); c1 = fmaf(bfhi(u2), w2, c1);
        d0 = fmaf(bflo(u3), w3, d0); d1 = fmaf(bfhi(u3), w3, d1);
    }
    for (; j < t; ++j) {
        unsigned pw = pack[j];
        float wm = (float)(pw >> 17) * (1.0f / 32767.0f);
        unsigned u = evb[(size_t)(pw & 0x1FFFFu) * 64 + lane];
        a0 = fmaf(bflo(u), wm, a0); a1 = fmaf(bfhi(u), wm, a1);
    }
    float acc0 = (a0 + b0) + (c0 + d0);
    float acc1 = (a1 + b1) + (c1 + d1);
    float rs = 1.0f / vrs[row];
    float wt = vweight[row] * 4.0f;
    float2 vr = *reinterpret_cast<const float2*>(&v[(size_t)row * DD + lane * 2]);
    float2 o = make_float2((vr.x * wt + acc0) * rs, (vr.y * wt + acc1) * rs);
    *reinterpret_cast<float2*>(&vout[(size_t)row * DD + lane * 2]) = o;
}

// ---------------------------------------------------------------------------
extern "C" void kernel_launch(void* const* d_in, const int* in_sizes, int n_in,
                              void* d_out, int out_size, void* d_ws, size_t ws_size,
                              hipStream_t stream)
{
    const float* v       = (const float*)d_in[0];
    const float* e       = (const float*)d_in[1];
    const int*   vidx    = (const int*)d_in[2];
    const int*   eidx    = (const int*)d_in[3];
    const float* vrw     = (const float*)d_in[4];
    const float* erw     = (const float*)d_in[5];
    const float* vrs     = (const float*)d_in[6];
    const float* ers     = (const float*)d_in[7];
    const float* Wv2e    = (const float*)d_in[8];
    const float* We2v    = (const float*)d_in[9];
    const float* bv      = (const float*)d_in[10];
    const float* be      = (const float*)d_in[11];
    const float* vweight = (const float*)d_in[12];

    const int N = in_sizes[0] / DD;
    const int E = in_sizes[1] / DD;
    const int M = in_sizes[2];

    float* vout = (float*)d_out;
    float* eout = vout + (size_t)N * DD;

    // workspace layout (evb aliases vwb; tmp shared between sides)
    char* wsb = (char*)d_ws;
    size_t off = 0;
    auto alloc = [&](size_t bytes) { char* p = wsb + off; off += (bytes + 255) & ~(size_t)255; return p; };
    unsigned* vwb   = (unsigned*)alloc((size_t)N * 64 * sizeof(unsigned));  // 25.6 MB (bf16)
    unsigned* evb   = vwb;                                                  // alias (12.8 MB used)
    int*   e_start = (int*)alloc((size_t)(E + 1) * sizeof(int));
    int*   v_start = (int*)alloc((size_t)(N + 1) * sizeof(int));
    int*   e_cnt   = (int*)alloc((size_t)E * sizeof(int));
    int*   v_cnt   = (int*)alloc((size_t)N * sizeof(int));
    int*   e_part  = (int*)alloc(1024 * sizeof(int));
    int*   v_part  = (int*)alloc(1024 * sizeof(int));
    int*   bcur    = (int*)alloc(MAXB * sizeof(int));
    unsigned* e_pack = (unsigned*)alloc((size_t)M * sizeof(unsigned));      // 4 MB
    unsigned* v_pack = (unsigned*)alloc((size_t)M * sizeof(unsigned));      // 4 MB
    int2*  tmp     = (int2*)alloc((size_t)M * sizeof(int2));                // 8 MB

    const int e_nb = (E + SCAN_CHUNK - 1) / SCAN_CHUNK;
    const int v_nb = (N + SCAN_CHUNK - 1) / SCAN_CHUNK;
    const int mblk = (M + 255) / 256;
    const int pblk = (M + PART_ELEMS - 1) / PART_ELEMS;

    // bucket shifts: smallest pow2 step with <= MAXB buckets
    auto calc_shift = [](int n) { int s = 0; while (((n + (1 << s) - 1) >> s) > MAXB) ++s; return s; };
    const int e_shift = calc_shift(E);
    const int v_shift = calc_shift(N);
    const int e_bk = (E + (1 << e_shift) - 1) >> e_shift;
    const int v_bk = (N + (1 << v_shift) - 1) >> v_shift;

    // --- counts + row starts ---
    hipMemsetAsync(e_cnt, 0, (size_t)E * sizeof(int), stream);
    hipMemsetAsync(v_cnt, 0, (size_t)N * sizeof(int), stream);
    hist_kernel<<<mblk, 256, 0, stream>>>(eidx, vidx, e_cnt, v_cnt, M);
    scan_reduce_kernel<<<e_nb, 1024, 0, stream>>>(e_cnt, e_part, E);
    scan_partials_kernel<<<1, 1024, 0, stream>>>(e_part, e_nb, e_start, E);
    scan_write_kernel<<<e_nb, 1024, 0, stream>>>(e_cnt, e_part, e_start, E);
    scan_reduce_kernel<<<v_nb, 1024, 0, stream>>>(v_cnt, v_part, N);
    scan_partials_kernel<<<1, 1024, 0, stream>>>(v_part, v_nb, v_start, N);
    scan_write_kernel<<<v_nb, 1024, 0, stream>>>(v_cnt, v_part, v_start, N);

    // --- e-side partition (LDS-binned) + place ---
    bucket_init_kernel<<<1, MAXB, 0, stream>>>(e_start, E, e_shift, e_bk, bcur);
    part_kernel<<<pblk, 256, 0, stream>>>(eidx, vidx, vrw, bcur, tmp, M, e_shift, e_bk);
    place_kernel<<<mblk, 256, 0, stream>>>(tmp, e_start, e_cnt, e_pack, M, mblk);

    // --- v-side partition + place ---
    bucket_init_kernel<<<1, MAXB, 0, stream>>>(v_start, N, v_shift, v_bk, bcur);
    part_kernel<<<pblk, 256, 0, stream>>>(vidx, eidx, erw, bcur, tmp, M, v_shift, v_bk);
    place_kernel<<<mblk, 256, 0, stream>>>(tmp, v_start, v_cnt, v_pack, M, mblk);

    // --- compute ---
    gemm_v2e_kernel<<<(N + TILE_R - 1) / TILE_R, GBLK, 0, stream>>>(v, Wv2e, bv, vweight, vwb, N);
    e_agg_kernel<<<(E + 3) / 4, 256, 0, stream>>>(e, vwb, e_start, e_pack, ers, eout, E);
    gemm_e2v_kernel<<<(E + TILE_R - 1) / TILE_R, GBLK, 0, stream>>>(eout, We2v, be, evb, E);
    v_agg_kernel<<<(N + 3) / 4, 256, 0, stream>>>(v, evb, v_start, v_pack, vrs, vweight, vout, N);
}

// Round 9
// 392.199 us; speedup vs baseline: 1.1426x; 1.1426x over previous
//
#include <hip/hip_runtime.h>
#include <cstddef>

#define DD 128
#define SCAN_CHUNK 2048   // 1024 threads x 2 elements
#define PART_ELEMS 4096   // elements per partition block (256 thr x 16)
#define MAXB 128          // max destination-range buckets
#define WT_LD 136         // padded bf16 leading dim (272 B rows, 16B-aligned, 2-way banks)

typedef __attribute__((ext_vector_type(8))) short bf16x8;
typedef __attribute__((ext_vector_type(4))) float f32x4;

// pack two f32 -> one u32 of 2 bf16 (RNE)
__device__ __forceinline__ unsigned bf16pk(float x, float y) {
    unsigned a = __float_as_uint(x);
    unsigned b = __float_as_uint(y);
    a = (a + 0x7FFFu + ((a >> 16) & 1u)) >> 16;
    b = (b + 0x7FFFu + ((b >> 16) & 1u)) >> 16;
    return a | (b << 16);
}
__device__ __forceinline__ unsigned short bf16r(float x) {
    unsigned u = __float_as_uint(x);
    return (unsigned short)((u + 0x7FFFu + ((u >> 16) & 1u)) >> 16);
}
__device__ __forceinline__ float bflo(unsigned u) { return __uint_as_float(u << 16); }
__device__ __forceinline__ float bfhi(unsigned u) { return __uint_as_float(u & 0xFFFF0000u); }

// bijective XCD-chunked block swizzle (m204 variant)
__device__ __forceinline__ int xcd_swz(int orig, int nwg) {
    int q = nwg >> 3, r = nwg & 7;
    int x = orig & 7, i = orig >> 3;
    return (x < r ? x * (q + 1) : r * (q + 1) + (x - r) * q) + i;
}

// ---------------------------------------------------------------------------
// histogram: count incidences per edge and per vertex (one pass over M)
__global__ void hist_kernel(const int* __restrict__ eidx, const int* __restrict__ vidx,
                            int* __restrict__ e_cnt, int* __restrict__ v_cnt, int M)
{
    int m = blockIdx.x * blockDim.x + threadIdx.x;
    if (m >= M) return;
    atomicAdd(&e_cnt[eidx[m]], 1);
    atomicAdd(&v_cnt[vidx[m]], 1);
}

// ---------------------------------------------------------------------------
// multi-block exclusive scan, phase 1: per-block (2048-elem chunk) sums
__global__ __launch_bounds__(1024)
void scan_reduce_kernel(const int* __restrict__ cnt, int* __restrict__ partial, int n)
{
    __shared__ int sdata[1024];
    int base = blockIdx.x * SCAN_CHUNK;
    int t = threadIdx.x;
    int i0 = base + 2 * t;
    int a = (i0 < n)     ? cnt[i0]     : 0;
    int b = (i0 + 1 < n) ? cnt[i0 + 1] : 0;
    sdata[t] = a + b;
    __syncthreads();
    for (int off = 512; off > 0; off >>= 1) {
        if (t < off) sdata[t] += sdata[t + off];
        __syncthreads();
    }
    if (t == 0) partial[blockIdx.x] = sdata[0];
}

// phase 2: exclusive scan of partials (nb <= 1024) in one block; writes total -> start[n]
__global__ __launch_bounds__(1024)
void scan_partials_kernel(int* __restrict__ partial, int nb, int* __restrict__ start, int n)
{
    __shared__ int sdata[1024];
    int t = threadIdx.x;
    int v = (t < nb) ? partial[t] : 0;
    sdata[t] = v;
    __syncthreads();
    int x = v;
    for (int off = 1; off < 1024; off <<= 1) {
        int y = (t >= off) ? sdata[t - off] : 0;
        __syncthreads();
        x += y;
        sdata[t] = x;
        __syncthreads();
    }
    if (t < nb) partial[t] = x - v;        // exclusive
    if (t == nb - 1) start[n] = x;         // grand total
}

// phase 3: per-chunk scan + chunk base -> exclusive start[]
__global__ __launch_bounds__(1024)
void scan_write_kernel(const int* __restrict__ cnt, const int* __restrict__ partial,
                       int* __restrict__ start, int n)
{
    __shared__ int sdata[1024];
    int base = blockIdx.x * SCAN_CHUNK;
    int t = threadIdx.x;
    int i0 = base + 2 * t;
    int a = (i0 < n)     ? cnt[i0]     : 0;
    int b = (i0 + 1 < n) ? cnt[i0 + 1] : 0;
    int s = a + b;
    sdata[t] = s;
    __syncthreads();
    int x = s;
    for (int off = 1; off < 1024; off <<= 1) {
        int y = (t >= off) ? sdata[t - off] : 0;
        __syncthreads();
        x += y;
        sdata[t] = x;
        __syncthreads();
    }
    int ex = partial[blockIdx.x] + x - s;
    if (i0 < n)     start[i0]     = ex;
    if (i0 + 1 < n) start[i0 + 1] = ex + a;
}

// ---------------------------------------------------------------------------
// bucket cursor init: bcur[b] = rstart[min(b<<shift, n)]
__global__ void bucket_init_kernel(const int* __restrict__ rstart, int n, int shift,
                                   int nb, int* __restrict__ bcur)
{
    int b = threadIdx.x;
    if (b >= nb) return;
    long long i = (long long)b << shift;
    if (i > n) i = n;
    bcur[b] = rstart[i];
}

// partition pass A: LDS-staged bucket binning
__global__ __launch_bounds__(256)
void part_kernel(const int* __restrict__ didx, const int* __restrict__ sidx,
                 const float* __restrict__ w, int* __restrict__ bcur,
                 int2* __restrict__ tmp, int M, int shift, int nb)
{
    __shared__ int lcnt[MAXB];
    __shared__ int lbase[MAXB];
    const int t = threadIdx.x;
    const int base = blockIdx.x * PART_ELEMS;
    const int end = min(base + PART_ELEMS, M);

    for (int i = t; i < nb; i += 256) lcnt[i] = 0;
    __syncthreads();
    for (int j = base + t; j < end; j += 256)
        atomicAdd(&lcnt[didx[j] >> shift], 1);
    __syncthreads();
    for (int i = t; i < nb; i += 256) {
        int c = lcnt[i];
        lbase[i] = c ? atomicAdd(&bcur[i], c) : 0;
        lcnt[i] = 0;
    }
    __syncthreads();
    for (int j = base + t; j < end; j += 256) {
        int d = didx[j];
        int b = d >> shift;
        int pos = lbase[b] + atomicAdd(&lcnt[b], 1);
        int wq = (int)(w[j] * 32767.0f + 0.5f);
        wq = wq < 32767 ? wq : 32767;
        tmp[pos] = make_int2(d | (wq << 17), sidx[j]);
    }
}

// partition pass B: stream bucket-grouped records; pack[p] = src | (w15 << 17)
__global__ __launch_bounds__(256)
void place_kernel(const int2* __restrict__ tmp, const int* __restrict__ rstart,
                  int* __restrict__ rcnt, unsigned* __restrict__ pack, int M, int nwg)
{
    int blk = xcd_swz(blockIdx.x, nwg);
    int j = blk * 256 + threadIdx.x;
    if (j >= M) return;
    int2 r = tmp[j];
    int d = r.x & 0x1FFFF;
    int p = rstart[d] + atomicSub(&rcnt[d], 1) - 1;
    pack[p] = (unsigned)r.y | (((unsigned)r.x >> 17) << 17);
}

// ---------------------------------------------------------------------------
// one-time: W [k][col] f32 -> Wt [col][k] bf16 (two matrices)
__global__ __launch_bounds__(256)
void conv_w_kernel(const float* __restrict__ W0, const float* __restrict__ W1,
                   unsigned short* __restrict__ Wt0, unsigned short* __restrict__ Wt1)
{
    int idx = blockIdx.x * 256 + threadIdx.x;   // 0..16383
    int k = idx >> 7, c = idx & 127;
    Wt0[c * 128 + k] = bf16r(W0[idx]);
    Wt1[c * 128 + k] = bf16r(W1[idx]);
}

// ---------------------------------------------------------------------------
// MFMA GEMM: outb(bf16 u32-pairs) = epilogue(A @ W + bias)
//   V2E: relu(.)*rowwt[row]     E2V: relu(.)*scale
// 256 thr / 4 waves, 64 rows per block, 16x16x32 bf16 MFMA, K=128, Ncols=128.
template<bool V2E>
__global__ __launch_bounds__(256)
void gemm_mfma_kernel(const float* __restrict__ A, const unsigned short* __restrict__ Wtg,
                      const float* __restrict__ bias, const float* __restrict__ rowwt,
                      unsigned* __restrict__ outb, int nrows, float scale)
{
    __shared__ unsigned short Wt[128 * WT_LD];   // 34816 B
    __shared__ unsigned short At[64 * WT_LD];    // 17408 B

    const int t = threadIdx.x;
    const int row0 = blockIdx.x * 64;

    // stage Wt: 128 rows x 128 bf16; 2 threads/row, 64 shorts (8 x uint4) each
    {
        int r = t >> 1, h = t & 1;
        const uint4* src = reinterpret_cast<const uint4*>(Wtg + r * 128 + h * 64);
        uint4* dst = reinterpret_cast<uint4*>(&Wt[r * WT_LD + h * 64]);
        #pragma unroll
        for (int i = 0; i < 8; ++i) dst[i] = src[i];
    }
    // stage At (f32 -> bf16, 32 floats per thread; 4 threads/row cover 128 cols)
    {
        int r = t >> 2, q = t & 3;
        int grow = row0 + r;
        uint4 o[4];
        if (grow < nrows) {
            const float4* src = reinterpret_cast<const float4*>(A + (size_t)grow * DD + q * 32);
            #pragma unroll
            for (int i = 0; i < 4; ++i) {
                float4 f0 = src[2 * i];
                float4 f1 = src[2 * i + 1];
                o[i].x = bf16pk(f0.x, f0.y);
                o[i].y = bf16pk(f0.z, f0.w);
                o[i].z = bf16pk(f1.x, f1.y);
                o[i].w = bf16pk(f1.z, f1.w);
            }
        } else {
            #pragma unroll
            for (int i = 0; i < 4; ++i) o[i] = make_uint4(0, 0, 0, 0);
        }
        uint4* dst = reinterpret_cast<uint4*>(&At[r * WT_LD + q * 32]);
        #pragma unroll
        for (int i = 0; i < 4; ++i) dst[i] = o[i];
    }
    __syncthreads();

    const int w  = t >> 6;         // wave 0..3
    const int l  = t & 63;
    const int lr = l & 15;         // A-row / B-col within tile
    const int lk = (l >> 4) * 8;   // k-offset base

    f32x4 acc[8];
    #pragma unroll
    for (int i = 0; i < 8; ++i) acc[i] = 0.0f;

    const int arow = w * 16 + lr;
    #pragma unroll
    for (int ks = 0; ks < 4; ++ks) {
        bf16x8 af = *reinterpret_cast<const bf16x8*>(&At[arow * WT_LD + lk + ks * 32]);
        #pragma unroll
        for (int ct = 0; ct < 8; ++ct) {
            bf16x8 bfr = *reinterpret_cast<const bf16x8*>(&Wt[(ct * 16 + lr) * WT_LD + lk + ks * 32]);
            acc[ct] = __builtin_amdgcn_mfma_f32_16x16x32_bf16(af, bfr, acc[ct], 0, 0, 0);
        }
    }

    // epilogue: bias + relu + scale, bf16 into own wave's At rows (no cross-wave hazard)
    float bcol[8];
    #pragma unroll
    for (int ct = 0; ct < 8; ++ct) bcol[ct] = bias[ct * 16 + lr];
    #pragma unroll
    for (int r = 0; r < 4; ++r) {
        int rl = w * 16 + (l >> 4) * 4 + r;
        int grow = row0 + rl;
        float rw = scale;
        if (V2E) rw = (grow < nrows) ? rowwt[grow] : 0.f;
        #pragma unroll
        for (int ct = 0; ct < 8; ++ct) {
            float val = fmaxf(acc[ct][r] + bcol[ct], 0.f) * rw;
            At[rl * WT_LD + ct * 16 + lr] = bf16r(val);
        }
    }
    // coalesced writeback (reads only this wave's rows; in-wave LDS ordering suffices)
    {
        int r = t >> 2, part = t & 3;
        int grow = row0 + r;
        if (grow < nrows) {
            const uint4* src = reinterpret_cast<const uint4*>(&At[r * WT_LD + part * 32]);
            uint4* dst = reinterpret_cast<uint4*>(outb + (size_t)grow * 64 + part * 16);
            dst[0] = src[0]; dst[1] = src[1]; dst[2] = src[2]; dst[3] = src[3];
        }
    }
}

// ---------------------------------------------------------------------------
// e-aggregation with 4x unrolled, MLP-exposed gather loop.
__global__ __launch_bounds__(256)
void e_agg_kernel(const float* __restrict__ e, const unsigned* __restrict__ vwb,
                  const int* __restrict__ start, const unsigned* __restrict__ pack,
                  const float* __restrict__ ers, float* __restrict__ eout, int E)
{
    int row = blockIdx.x * 4 + (threadIdx.x >> 6);
    if (row >= E) return;
    int lane = threadIdx.x & 63;
    int s = start[row], t = start[row + 1];
    float a0 = 0.f, a1 = 0.f, b0 = 0.f, b1 = 0.f, c0 = 0.f, c1 = 0.f, d0 = 0.f, d1 = 0.f;
    int j = s;
    for (; j + 4 <= t; j += 4) {
        unsigned pw0 = pack[j];
        unsigned pw1 = pack[j + 1];
        unsigned pw2 = pack[j + 2];
        unsigned pw3 = pack[j + 3];
        unsigned u0 = vwb[(size_t)(pw0 & 0x1FFFFu) * 64 + lane];
        unsigned u1 = vwb[(size_t)(pw1 & 0x1FFFFu) * 64 + lane];
        unsigned u2 = vwb[(size_t)(pw2 & 0x1FFFFu) * 64 + lane];
        unsigned u3 = vwb[(size_t)(pw3 & 0x1FFFFu) * 64 + lane];
        float w0 = (float)(pw0 >> 17) * (1.0f / 32767.0f);
        float w1 = (float)(pw1 >> 17) * (1.0f / 32767.0f);
        float w2 = (float)(pw2 >> 17) * (1.0f / 32767.0f);
        float w3 = (float)(pw3 >> 17) * (1.0f / 32767.0f);
        a0 = fmaf(bflo(u0), w0, a0); a1 = fmaf(bfhi(u0), w0, a1);
        b0 = fmaf(bflo(u1), w1, b0); b1 = fmaf(bfhi(u1), w1, b1);
        c0 = fmaf(bflo(u2), w2, c0); c1 = fmaf(bfhi(u2), w2, c1);
        d0 = fmaf(bflo(u3), w3, d0); d1 = fmaf(bfhi(u3), w3, d1);
    }
    for (; j < t; ++j) {
        unsigned pw = pack[j];
        float wm = (float)(pw >> 17) * (1.0f / 32767.0f);
        unsigned u = vwb[(size_t)(pw & 0x1FFFFu) * 64 + lane];
        a0 = fmaf(bflo(u), wm, a0); a1 = fmaf(bfhi(u), wm, a1);
    }
    float acc0 = (a0 + b0) + (c0 + d0);
    float acc1 = (a1 + b1) + (c1 + d1);
    float rs = 1.0f / ers[row];
    float2 er = *reinterpret_cast<const float2*>(&e[(size_t)row * DD + lane * 2]);
    float2 o = make_float2((er.x + acc0) * rs, (er.y + acc1) * rs);
    *reinterpret_cast<float2*>(&eout[(size_t)row * DD + lane * 2]) = o;
}

// ---------------------------------------------------------------------------
// v-aggregation, same structure.
__global__ __launch_bounds__(256)
void v_agg_kernel(const float* __restrict__ v, const unsigned* __restrict__ evb,
                  const int* __restrict__ start, const unsigned* __restrict__ pack,
                  const float* __restrict__ vrs, const float* __restrict__ vweight,
                  float* __restrict__ vout, int N)
{
    int row = blockIdx.x * 4 + (threadIdx.x >> 6);
    if (row >= N) return;
    int lane = threadIdx.x & 63;
    int s = start[row], t = start[row + 1];
    float a0 = 0.f, a1 = 0.f, b0 = 0.f, b1 = 0.f, c0 = 0.f, c1 = 0.f, d0 = 0.f, d1 = 0.f;
    int j = s;
    for (; j + 4 <= t; j += 4) {
        unsigned pw0 = pack[j];
        unsigned pw1 = pack[j + 1];
        unsigned pw2 = pack[j + 2];
        unsigned pw3 = pack[j + 3];
        unsigned u0 = evb[(size_t)(pw0 & 0x1FFFFu) * 64 + lane];
        unsigned u1 = evb[(size_t)(pw1 & 0x1FFFFu) * 64 + lane];
        unsigned u2 = evb[(size_t)(pw2 & 0x1FFFFu) * 64 + lane];
        unsigned u3 = evb[(size_t)(pw3 & 0x1FFFFu) * 64 + lane];
        float w0 = (float)(pw0 >> 17) * (1.0f / 32767.0f);
        float w1 = (float)(pw1 >> 17) * (1.0f / 32767.0f);
        float w2 = (float)(pw2 >> 17) * (1.0f / 32767.0f);
        float w3 = (float)(pw3 >> 17) * (1.0f / 32767.0f);
        a0 = fmaf(bflo(u0), w0, a0); a1 = fmaf(bfhi(u0), w0, a1);
        b0 = fmaf(bflo(u1), w1, b0); b1 = fmaf(bfhi(u1), w1, b1);
        c0 = fmaf(bflo(u2), w2, c0); c1 = fmaf(bfhi(u2), w2, c1);
        d0 = fmaf(bflo(u3), w3, d0); d1 = fmaf(bfhi(u3), w3, d1);
    }
    for (; j < t; ++j) {
        unsigned pw = pack[j];
        float wm = (float)(pw >> 17) * (1.0f / 32767.0f);
        unsigned u = evb[(size_t)(pw & 0x1FFFFu) * 64 + lane];
        a0 = fmaf(bflo(u), wm, a0); a1 = fmaf(bfhi(u), wm, a1);
    }
    float acc0 = (a0 + b0) + (c0 + d0);
    float acc1 = (a1 + b1) + (c1 + d1);
    float rs = 1.0f / vrs[row];
    float wt = vweight[row] * 4.0f;
    float2 vr = *reinterpret_cast<const float2*>(&v[(size_t)row * DD + lane * 2]);
    float2 o = make_float2((vr.x * wt + acc0) * rs, (vr.y * wt + acc1) * rs);
    *reinterpret_cast<float2*>(&vout[(size_t)row * DD + lane * 2]) = o;
}

// ---------------------------------------------------------------------------
extern "C" void kernel_launch(void* const* d_in, const int* in_sizes, int n_in,
                              void* d_out, int out_size, void* d_ws, size_t ws_size,
                              hipStream_t stream)
{
    const float* v       = (const float*)d_in[0];
    const float* e       = (const float*)d_in[1];
    const int*   vidx    = (const int*)d_in[2];
    const int*   eidx    = (const int*)d_in[3];
    const float* vrw     = (const float*)d_in[4];
    const float* erw     = (const float*)d_in[5];
    const float* vrs     = (const float*)d_in[6];
    const float* ers     = (const float*)d_in[7];
    const float* Wv2e    = (const float*)d_in[8];
    const float* We2v    = (const float*)d_in[9];
    const float* bv      = (const float*)d_in[10];
    const float* be      = (const float*)d_in[11];
    const float* vweight = (const float*)d_in[12];

    const int N = in_sizes[0] / DD;
    const int E = in_sizes[1] / DD;
    const int M = in_sizes[2];

    float* vout = (float*)d_out;
    float* eout = vout + (size_t)N * DD;

    // workspace layout (evb aliases vwb; tmp shared between sides)
    char* wsb = (char*)d_ws;
    size_t off = 0;
    auto alloc = [&](size_t bytes) { char* p = wsb + off; off += (bytes + 255) & ~(size_t)255; return p; };
    unsigned* vwb   = (unsigned*)alloc((size_t)N * 64 * sizeof(unsigned));  // 25.6 MB (bf16)
    unsigned* evb   = vwb;                                                  // alias
    int*   e_start = (int*)alloc((size_t)(E + 1) * sizeof(int));
    int*   v_start = (int*)alloc((size_t)(N + 1) * sizeof(int));
    int*   e_cnt   = (int*)alloc((size_t)E * sizeof(int));
    int*   v_cnt   = (int*)alloc((size_t)N * sizeof(int));
    int*   e_part  = (int*)alloc(1024 * sizeof(int));
    int*   v_part  = (int*)alloc(1024 * sizeof(int));
    int*   bcur    = (int*)alloc(MAXB * sizeof(int));
    unsigned short* Wt0 = (unsigned short*)alloc(DD * DD * sizeof(unsigned short)); // 32 KB
    unsigned short* Wt1 = (unsigned short*)alloc(DD * DD * sizeof(unsigned short)); // 32 KB
    unsigned* e_pack = (unsigned*)alloc((size_t)M * sizeof(unsigned));      // 4 MB
    unsigned* v_pack = (unsigned*)alloc((size_t)M * sizeof(unsigned));      // 4 MB
    int2*  tmp     = (int2*)alloc((size_t)M * sizeof(int2));                // 8 MB

    const int e_nb = (E + SCAN_CHUNK - 1) / SCAN_CHUNK;
    const int v_nb = (N + SCAN_CHUNK - 1) / SCAN_CHUNK;
    const int mblk = (M + 255) / 256;
    const int pblk = (M + PART_ELEMS - 1) / PART_ELEMS;

    auto calc_shift = [](int n) { int s = 0; while (((n + (1 << s) - 1) >> s) > MAXB) ++s; return s; };
    const int e_shift = calc_shift(E);
    const int v_shift = calc_shift(N);
    const int e_bk = (E + (1 << e_shift) - 1) >> e_shift;
    const int v_bk = (N + (1 << v_shift) - 1) >> v_shift;

    // --- one-time W transpose/convert (overlaps with CSR build) ---
    conv_w_kernel<<<64, 256, 0, stream>>>(Wv2e, We2v, Wt0, Wt1);

    // --- counts + row starts ---
    hipMemsetAsync(e_cnt, 0, (size_t)E * sizeof(int), stream);
    hipMemsetAsync(v_cnt, 0, (size_t)N * sizeof(int), stream);
    hist_kernel<<<mblk, 256, 0, stream>>>(eidx, vidx, e_cnt, v_cnt, M);
    scan_reduce_kernel<<<e_nb, 1024, 0, stream>>>(e_cnt, e_part, E);
    scan_partials_kernel<<<1, 1024, 0, stream>>>(e_part, e_nb, e_start, E);
    scan_write_kernel<<<e_nb, 1024, 0, stream>>>(e_cnt, e_part, e_start, E);
    scan_reduce_kernel<<<v_nb, 1024, 0, stream>>>(v_cnt, v_part, N);
    scan_partials_kernel<<<1, 1024, 0, stream>>>(v_part, v_nb, v_start, N);
    scan_write_kernel<<<v_nb, 1024, 0, stream>>>(v_cnt, v_part, v_start, N);

    // --- e-side partition (LDS-binned) + place ---
    bucket_init_kernel<<<1, MAXB, 0, stream>>>(e_start, E, e_shift, e_bk, bcur);
    part_kernel<<<pblk, 256, 0, stream>>>(eidx, vidx, vrw, bcur, tmp, M, e_shift, e_bk);
    place_kernel<<<mblk, 256, 0, stream>>>(tmp, e_start, e_cnt, e_pack, M, mblk);

    // --- v-side partition + place ---
    bucket_init_kernel<<<1, MAXB, 0, stream>>>(v_start, N, v_shift, v_bk, bcur);
    part_kernel<<<pblk, 256, 0, stream>>>(vidx, eidx, erw, bcur, tmp, M, v_shift, v_bk);
    place_kernel<<<mblk, 256, 0, stream>>>(tmp, v_start, v_cnt, v_pack, M, mblk);

    // --- compute ---
    gemm_mfma_kernel<true><<<(N + 63) / 64, 256, 0, stream>>>(v, Wt0, bv, vweight, vwb, N, 1.0f);
    e_agg_kernel<<<(E + 3) / 4, 256, 0, stream>>>(e, vwb, e_start, e_pack, ers, eout, E);
    gemm_mfma_kernel<false><<<(E + 63) / 64, 256, 0, stream>>>(eout, Wt1, be, nullptr, evb, E, 1.0f / 3.0f);
    v_agg_kernel<<<(N + 3) / 4, 256, 0, stream>>>(v, evb, v_start, v_pack, vrs, vweight, vout, N);
}

// Round 10
// 238.604 us; speedup vs baseline: 1.8781x; 1.6437x over previous
//
#include <hip/hip_runtime.h>
#include <cstddef>

#define DD 128
#define PART_ELEMS 4096   // elements per partition block (256 thr x 16)
#define MAXB 256          // max destination-range buckets
#define MAXW 512          // max rows per bucket (LDS counter width)
#define WT_LD 136         // padded bf16 leading dim

typedef __attribute__((ext_vector_type(8))) short bf16x8;
typedef __attribute__((ext_vector_type(4))) float f32x4;

__device__ __forceinline__ unsigned bf16pk(float x, float y) {
    unsigned a = __float_as_uint(x);
    unsigned b = __float_as_uint(y);
    a = (a + 0x7FFFu + ((a >> 16) & 1u)) >> 16;
    b = (b + 0x7FFFu + ((b >> 16) & 1u)) >> 16;
    return a | (b << 16);
}
__device__ __forceinline__ unsigned short bf16r(float x) {
    unsigned u = __float_as_uint(x);
    return (unsigned short)((u + 0x7FFFu + ((u >> 16) & 1u)) >> 16);
}
__device__ __forceinline__ float bflo(unsigned u) { return __uint_as_float(u << 16); }
__device__ __forceinline__ float bfhi(unsigned u) { return __uint_as_float(u & 0xFFFF0000u); }

// ---------------------------------------------------------------------------
// bucket cursor init: bcur[b] = b * cap (absolute offsets into tmp)
__global__ void binit_kernel(int* __restrict__ bcur, int cap)
{
    bcur[threadIdx.x] = threadIdx.x * cap;
}

// partition: LDS-staged bucket binning into fixed-capacity tmp regions
__global__ __launch_bounds__(256)
void part_kernel(const int* __restrict__ didx, const int* __restrict__ sidx,
                 const float* __restrict__ w, int* __restrict__ bcur,
                 int2* __restrict__ tmp, int M, int shift, int nb)
{
    __shared__ int lcnt[MAXB];
    __shared__ int lbase[MAXB];
    const int t = threadIdx.x;
    const int base = blockIdx.x * PART_ELEMS;
    const int end = min(base + PART_ELEMS, M);

    if (t < nb) lcnt[t] = 0;
    __syncthreads();
    for (int j = base + t; j < end; j += 256)
        atomicAdd(&lcnt[didx[j] >> shift], 1);
    __syncthreads();
    if (t < nb) {
        int c = lcnt[t];
        lbase[t] = c ? atomicAdd(&bcur[t], c) : 0;
        lcnt[t] = 0;
    }
    __syncthreads();
    for (int j = base + t; j < end; j += 256) {
        int d = didx[j];
        int b = d >> shift;
        int pos = lbase[b] + atomicAdd(&lcnt[b], 1);
        int wq = (int)(w[j] * 32767.0f + 0.5f);
        wq = wq < 32767 ? wq : 32767;
        tmp[pos] = make_int2(d | (wq << 17), sidx[j]);
    }
}

// bucket scan: one block; cnt[b] = bcur[b]-b*cap; exclusive scan -> bbase; start[n]=M
__global__ __launch_bounds__(256)
void bucket_scan_kernel(const int* __restrict__ bcur, int cap, int nb,
                        int* __restrict__ bbase, int* __restrict__ start, int n, int M)
{
    __shared__ int sdata[256];
    int t = threadIdx.x;
    int c = (t < nb) ? (bcur[t] - t * cap) : 0;
    sdata[t] = c;
    __syncthreads();
    int x = c;
    for (int off = 1; off < 256; off <<= 1) {
        int y = (t >= off) ? sdata[t - off] : 0;
        __syncthreads();
        x += y;
        sdata[t] = x;
        __syncthreads();
    }
    if (t < nb) bbase[t] = x - c;   // exclusive
    if (t == 0) start[n] = M;
}

// fine pass: one block per bucket. LDS histogram + scan over the bucket's row
// range, write start[] slice, then place records into pack (L2-window writes).
__global__ __launch_bounds__(256)
void fine_kernel(const int2* __restrict__ tmp, const int* __restrict__ bcur,
                 const int* __restrict__ bbase, int cap, int shift, int n,
                 int* __restrict__ start, unsigned* __restrict__ pack)
{
    __shared__ int lcnt[MAXW];
    __shared__ int lstart[MAXW];
    __shared__ int sdata[256];

    const int b = blockIdx.x;
    const int t = threadIdx.x;
    const int d0 = b << shift;
    const int width = min(1 << shift, n - d0);
    const int tbase = b * cap;
    const int nrec = bcur[b] - tbase;
    const int pbase = bbase[b];

    lcnt[t] = 0; lcnt[t + 256] = 0;
    __syncthreads();
    // pass 1: count
    for (int j = t; j < nrec; j += 256)
        atomicAdd(&lcnt[(tmp[tbase + j].x & 0x1FFFF) - d0], 1);
    __syncthreads();
    // LDS exclusive scan over 512 (pairs per thread)
    int a = lcnt[2 * t], bb = lcnt[2 * t + 1];
    int s = a + bb;
    sdata[t] = s;
    __syncthreads();
    int x = s;
    for (int off = 1; off < 256; off <<= 1) {
        int y = (t >= off) ? sdata[t - off] : 0;
        __syncthreads();
        x += y;
        sdata[t] = x;
        __syncthreads();
    }
    int ex = x - s;
    lstart[2 * t] = ex;
    lstart[2 * t + 1] = ex + a;
    lcnt[2 * t] = 0; lcnt[2 * t + 1] = 0;   // reuse as cursors
    __syncthreads();
    // write start slice
    for (int i = t; i < width; i += 256)
        start[d0 + i] = pbase + lstart[i];
    // pass 2: place
    for (int j = t; j < nrec; j += 256) {
        int2 r = tmp[tbase + j];
        int di = (r.x & 0x1FFFF) - d0;
        int pos = pbase + lstart[di] + atomicAdd(&lcnt[di], 1);
        pack[pos] = (unsigned)r.y | (((unsigned)r.x >> 17) << 17);
    }
}

// ---------------------------------------------------------------------------
// one-time: W [k][col] f32 -> Wt [col][k] bf16 (two matrices)
__global__ __launch_bounds__(256)
void conv_w_kernel(const float* __restrict__ W0, const float* __restrict__ W1,
                   unsigned short* __restrict__ Wt0, unsigned short* __restrict__ Wt1)
{
    int idx = blockIdx.x * 256 + threadIdx.x;
    int k = idx >> 7, c = idx & 127;
    Wt0[c * 128 + k] = bf16r(W0[idx]);
    Wt1[c * 128 + k] = bf16r(W1[idx]);
}

// ---------------------------------------------------------------------------
// MFMA GEMM: outb(bf16 u32-pairs) = epilogue(A @ W + bias)
template<bool V2E>
__global__ __launch_bounds__(256)
void gemm_mfma_kernel(const float* __restrict__ A, const unsigned short* __restrict__ Wtg,
                      const float* __restrict__ bias, const float* __restrict__ rowwt,
                      unsigned* __restrict__ outb, int nrows, float scale)
{
    __shared__ unsigned short Wt[128 * WT_LD];
    __shared__ unsigned short At[64 * WT_LD];

    const int t = threadIdx.x;
    const int row0 = blockIdx.x * 64;

    {
        int r = t >> 1, h = t & 1;
        const uint4* src = reinterpret_cast<const uint4*>(Wtg + r * 128 + h * 64);
        uint4* dst = reinterpret_cast<uint4*>(&Wt[r * WT_LD + h * 64]);
        #pragma unroll
        for (int i = 0; i < 8; ++i) dst[i] = src[i];
    }
    {
        int r = t >> 2, q = t & 3;
        int grow = row0 + r;
        uint4 o[4];
        if (grow < nrows) {
            const float4* src = reinterpret_cast<const float4*>(A + (size_t)grow * DD + q * 32);
            #pragma unroll
            for (int i = 0; i < 4; ++i) {
                float4 f0 = src[2 * i];
                float4 f1 = src[2 * i + 1];
                o[i].x = bf16pk(f0.x, f0.y);
                o[i].y = bf16pk(f0.z, f0.w);
                o[i].z = bf16pk(f1.x, f1.y);
                o[i].w = bf16pk(f1.z, f1.w);
            }
        } else {
            #pragma unroll
            for (int i = 0; i < 4; ++i) o[i] = make_uint4(0, 0, 0, 0);
        }
        uint4* dst = reinterpret_cast<uint4*>(&At[r * WT_LD + q * 32]);
        #pragma unroll
        for (int i = 0; i < 4; ++i) dst[i] = o[i];
    }
    __syncthreads();

    const int w  = t >> 6;
    const int l  = t & 63;
    const int lr = l & 15;
    const int lk = (l >> 4) * 8;

    f32x4 acc[8];
    #pragma unroll
    for (int i = 0; i < 8; ++i) acc[i] = 0.0f;

    const int arow = w * 16 + lr;
    #pragma unroll
    for (int ks = 0; ks < 4; ++ks) {
        bf16x8 af = *reinterpret_cast<const bf16x8*>(&At[arow * WT_LD + lk + ks * 32]);
        #pragma unroll
        for (int ct = 0; ct < 8; ++ct) {
            bf16x8 bfr = *reinterpret_cast<const bf16x8*>(&Wt[(ct * 16 + lr) * WT_LD + lk + ks * 32]);
            acc[ct] = __builtin_amdgcn_mfma_f32_16x16x32_bf16(af, bfr, acc[ct], 0, 0, 0);
        }
    }

    float bcol[8];
    #pragma unroll
    for (int ct = 0; ct < 8; ++ct) bcol[ct] = bias[ct * 16 + lr];
    #pragma unroll
    for (int r = 0; r < 4; ++r) {
        int rl = w * 16 + (l >> 4) * 4 + r;
        int grow = row0 + rl;
        float rw = scale;
        if (V2E) rw = (grow < nrows) ? rowwt[grow] : 0.f;
        #pragma unroll
        for (int ct = 0; ct < 8; ++ct) {
            float val = fmaxf(acc[ct][r] + bcol[ct], 0.f) * rw;
            At[rl * WT_LD + ct * 16 + lr] = bf16r(val);
        }
    }
    {
        int r = t >> 2, part = t & 3;
        int grow = row0 + r;
        if (grow < nrows) {
            const uint4* src = reinterpret_cast<const uint4*>(&At[r * WT_LD + part * 32]);
            uint4* dst = reinterpret_cast<uint4*>(outb + (size_t)grow * 64 + part * 16);
            dst[0] = src[0]; dst[1] = src[1]; dst[2] = src[2]; dst[3] = src[3];
        }
    }
}

// ---------------------------------------------------------------------------
// e-aggregation with 4x unrolled, MLP-exposed gather loop.
__global__ __launch_bounds__(256)
void e_agg_kernel(const float* __restrict__ e, const unsigned* __restrict__ vwb,
                  const int* __restrict__ start, const unsigned* __restrict__ pack,
                  const float* __restrict__ ers, float* __restrict__ eout, int E)
{
    int row = blockIdx.x * 4 + (threadIdx.x >> 6);
    if (row >= E) return;
    int lane = threadIdx.x & 63;
    int s = start[row], t = start[row + 1];
    float a0 = 0.f, a1 = 0.f, b0 = 0.f, b1 = 0.f, c0 = 0.f, c1 = 0.f, d0 = 0.f, d1 = 0.f;
    int j = s;
    for (; j + 4 <= t; j += 4) {
        unsigned pw0 = pack[j];
        unsigned pw1 = pack[j + 1];
        unsigned pw2 = pack[j + 2];
        unsigned pw3 = pack[j + 3];
        unsigned u0 = vwb[(size_t)(pw0 & 0x1FFFFu) * 64 + lane];
        unsigned u1 = vwb[(size_t)(pw1 & 0x1FFFFu) * 64 + lane];
        unsigned u2 = vwb[(size_t)(pw2 & 0x1FFFFu) * 64 + lane];
        unsigned u3 = vwb[(size_t)(pw3 & 0x1FFFFu) * 64 + lane];
        float w0 = (float)(pw0 >> 17) * (1.0f / 32767.0f);
        float w1 = (float)(pw1 >> 17) * (1.0f / 32767.0f);
        float w2 = (float)(pw2 >> 17) * (1.0f / 32767.0f);
        float w3 = (float)(pw3 >> 17) * (1.0f / 32767.0f);
        a0 = fmaf(bflo(u0), w0, a0); a1 = fmaf(bfhi(u0), w0, a1);
        b0 = fmaf(bflo(u1), w1, b0); b1 = fmaf(bfhi(u1), w1, b1);
        c0 = fmaf(bflo(u2), w2, c0); c1 = fmaf(bfhi(u2), w2, c1);
        d0 = fmaf(bflo(u3), w3, d0); d1 = fmaf(bfhi(u3), w3, d1);
    }
    for (; j < t; ++j) {
        unsigned pw = pack[j];
        float wm = (float)(pw >> 17) * (1.0f / 32767.0f);
        unsigned u = vwb[(size_t)(pw & 0x1FFFFu) * 64 + lane];
        a0 = fmaf(bflo(u), wm, a0); a1 = fmaf(bfhi(u), wm, a1);
    }
    float acc0 = (a0 + b0) + (c0 + d0);
    float acc1 = (a1 + b1) + (c1 + d1);
    float rs = 1.0f / ers[row];
    float2 er = *reinterpret_cast<const float2*>(&e[(size_t)row * DD + lane * 2]);
    float2 o = make_float2((er.x + acc0) * rs, (er.y + acc1) * rs);
    *reinterpret_cast<float2*>(&eout[(size_t)row * DD + lane * 2]) = o;
}

// ---------------------------------------------------------------------------
// v-aggregation, same structure.
__global__ __launch_bounds__(256)
void v_agg_kernel(const float* __restrict__ v, const unsigned* __restrict__ evb,
                  const int* __restrict__ start, const unsigned* __restrict__ pack,
                  const float* __restrict__ vrs, const float* __restrict__ vweight,
                  float* __restrict__ vout, int N)
{
    int row = blockIdx.x * 4 + (threadIdx.x >> 6);
    if (row >= N) return;
    int lane = threadIdx.x & 63;
    int s = start[row], t = start[row + 1];
    float a0 = 0.f, a1 = 0.f, b0 = 0.f, b1 = 0.f, c0 = 0.f, c1 = 0.f, d0 = 0.f, d1 = 0.f;
    int j = s;
    for (; j + 4 <= t; j += 4) {
        unsigned pw0 = pack[j];
        unsigned pw1 = pack[j + 1];
        unsigned pw2 = pack[j + 2];
        unsigned pw3 = pack[j + 3];
        unsigned u0 = evb[(size_t)(pw0 & 0x1FFFFu) * 64 + lane];
        unsigned u1 = evb[(size_t)(pw1 & 0x1FFFFu) * 64 + lane];
        unsigned u2 = evb[(size_t)(pw2 & 0x1FFFFu) * 64 + lane];
        unsigned u3 = evb[(size_t)(pw3 & 0x1FFFFu) * 64 + lane];
        float w0 = (float)(pw0 >> 17) * (1.0f / 32767.0f);
        float w1 = (float)(pw1 >> 17) * (1.0f / 32767.0f);
        float w2 = (float)(pw2 >> 17) * (1.0f / 32767.0f);
        float w3 = (float)(pw3 >> 17) * (1.0f / 32767.0f);
        a0 = fmaf(bflo(u0), w0, a0); a1 = fmaf(bfhi(u0), w0, a1);
        b0 = fmaf(bflo(u1), w1, b0); b1 = fmaf(bfhi(u1), w1, b1);
        c0 = fmaf(bflo(u2), w2, c0); c1 = fmaf(bfhi(u2), w2, c1);
        d0 = fmaf(bflo(u3), w3, d0); d1 = fmaf(bfhi(u3), w3, d1);
    }
    for (; j < t; ++j) {
        unsigned pw = pack[j];
        float wm = (float)(pw >> 17) * (1.0f / 32767.0f);
        unsigned u = evb[(size_t)(pw & 0x1FFFFu) * 64 + lane];
        a0 = fmaf(bflo(u), wm, a0); a1 = fmaf(bfhi(u), wm, a1);
    }
    float acc0 = (a0 + b0) + (c0 + d0);
    float acc1 = (a1 + b1) + (c1 + d1);
    float rs = 1.0f / vrs[row];
    float wt = vweight[row] * 4.0f;
    float2 vr = *reinterpret_cast<const float2*>(&v[(size_t)row * DD + lane * 2]);
    float2 o = make_float2((vr.x * wt + acc0) * rs, (vr.y * wt + acc1) * rs);
    *reinterpret_cast<float2*>(&vout[(size_t)row * DD + lane * 2]) = o;
}

// ---------------------------------------------------------------------------
extern "C" void kernel_launch(void* const* d_in, const int* in_sizes, int n_in,
                              void* d_out, int out_size, void* d_ws, size_t ws_size,
                              hipStream_t stream)
{
    const float* v       = (const float*)d_in[0];
    const float* e       = (const float*)d_in[1];
    const int*   vidx    = (const int*)d_in[2];
    const int*   eidx    = (const int*)d_in[3];
    const float* vrw     = (const float*)d_in[4];
    const float* erw     = (const float*)d_in[5];
    const float* vrs     = (const float*)d_in[6];
    const float* ers     = (const float*)d_in[7];
    const float* Wv2e    = (const float*)d_in[8];
    const float* We2v    = (const float*)d_in[9];
    const float* bv      = (const float*)d_in[10];
    const float* be      = (const float*)d_in[11];
    const float* vweight = (const float*)d_in[12];

    const int N = in_sizes[0] / DD;
    const int E = in_sizes[1] / DD;
    const int M = in_sizes[2];

    float* vout = (float*)d_out;
    float* eout = vout + (size_t)N * DD;

    // workspace layout (evb aliases vwb; tmp shared between sides)
    char* wsb = (char*)d_ws;
    size_t off = 0;
    auto alloc = [&](size_t bytes) { char* p = wsb + off; off += (bytes + 255) & ~(size_t)255; return p; };
    unsigned* vwb   = (unsigned*)alloc((size_t)N * 64 * sizeof(unsigned));  // 25.6 MB (bf16)
    unsigned* evb   = vwb;                                                  // alias
    int*   e_start = (int*)alloc((size_t)(E + 1) * sizeof(int));
    int*   v_start = (int*)alloc((size_t)(N + 1) * sizeof(int));
    int*   bcur    = (int*)alloc(MAXB * sizeof(int));
    int*   bbase   = (int*)alloc(MAXB * sizeof(int));
    unsigned short* Wt0 = (unsigned short*)alloc(DD * DD * sizeof(unsigned short));
    unsigned short* Wt1 = (unsigned short*)alloc(DD * DD * sizeof(unsigned short));
    unsigned* e_pack = (unsigned*)alloc((size_t)M * sizeof(unsigned));      // 4 MB
    unsigned* v_pack = (unsigned*)alloc((size_t)M * sizeof(unsigned));      // 4 MB
    int2*  tmp     = (int2*)alloc((size_t)M * 2 * sizeof(int2));            // 16 MB (cap slack)

    const int pblk = (M + PART_ELEMS - 1) / PART_ELEMS;

    // bucket geometry: smallest pow2 step with <= MAXB buckets AND width <= MAXW
    auto calc_shift = [](int n) {
        int s = 0;
        while (((n + (1 << s) - 1) >> s) > MAXB) ++s;
        return s;
    };
    const int e_shift = calc_shift(E);
    const int v_shift = calc_shift(N);
    const int e_bk = (E + (1 << e_shift) - 1) >> e_shift;
    const int v_bk = (N + (1 << v_shift) - 1) >> v_shift;
    // per-bucket tmp capacity: 1.5x mean (uniform multinomial, >30 sigma slack)
    const int e_cap = ((M / e_bk) * 3) / 2 + 256;
    const int v_cap = ((M / v_bk) * 3) / 2 + 256;

    // --- one-time W transpose/convert ---
    conv_w_kernel<<<64, 256, 0, stream>>>(Wv2e, We2v, Wt0, Wt1);

    // --- e-side CSR build (no global histogram, no global fine atomics) ---
    binit_kernel<<<1, MAXB, 0, stream>>>(bcur, e_cap);
    part_kernel<<<pblk, 256, 0, stream>>>(eidx, vidx, vrw, bcur, tmp, M, e_shift, e_bk);
    bucket_scan_kernel<<<1, 256, 0, stream>>>(bcur, e_cap, e_bk, bbase, e_start, E, M);
    fine_kernel<<<e_bk, 256, 0, stream>>>(tmp, bcur, bbase, e_cap, e_shift, E, e_start, e_pack);

    // --- v2e GEMM can start as soon as possible (independent of CSR) ---
    gemm_mfma_kernel<true><<<(N + 63) / 64, 256, 0, stream>>>(v, Wt0, bv, vweight, vwb, N, 1.0f);

    // --- e-aggregation ---
    e_agg_kernel<<<(E + 3) / 4, 256, 0, stream>>>(e, vwb, e_start, e_pack, ers, eout, E);

    // --- v-side CSR build (overlappable with e_agg only via stream order; keep serial) ---
    binit_kernel<<<1, MAXB, 0, stream>>>(bcur, v_cap);
    part_kernel<<<pblk, 256, 0, stream>>>(vidx, eidx, erw, bcur, tmp, M, v_shift, v_bk);
    bucket_scan_kernel<<<1, 256, 0, stream>>>(bcur, v_cap, v_bk, bbase, v_start, N, M);
    fine_kernel<<<v_bk, 256, 0, stream>>>(tmp, bcur, bbase, v_cap, v_shift, N, v_start, v_pack);

    // --- e2v GEMM + v-aggregation ---
    gemm_mfma_kernel<false><<<(E + 63) / 64, 256, 0, stream>>>(eout, Wt1, be, nullptr, evb, E, 1.0f / 3.0f);
    v_agg_kernel<<<(N + 3) / 4, 256, 0, stream>>>(v, evb, v_start, v_pack, vrs, vweight, vout, N);
}

// Round 11
// 191.396 us; speedup vs baseline: 2.3413x; 1.2466x over previous
//
#include <hip/hip_runtime.h>
#include <cstddef>

#define DD 128
#define PART_ELEMS 4096   // elements per partition block (256 thr x 16)
#define MAXB 256          // max destination-range buckets
#define MAXW 512          // max rows per bucket (LDS counter width)
#define WT_LD 136         // padded bf16 leading dim

typedef __attribute__((ext_vector_type(8))) short bf16x8;
typedef __attribute__((ext_vector_type(4))) float f32x4;

__device__ __forceinline__ unsigned bf16pk(float x, float y) {
    unsigned a = __float_as_uint(x);
    unsigned b = __float_as_uint(y);
    a = (a + 0x7FFFu + ((a >> 16) & 1u)) >> 16;
    b = (b + 0x7FFFu + ((b >> 16) & 1u)) >> 16;
    return a | (b << 16);
}
__device__ __forceinline__ unsigned short bf16r(float x) {
    unsigned u = __float_as_uint(x);
    return (unsigned short)((u + 0x7FFFu + ((u >> 16) & 1u)) >> 16);
}
__device__ __forceinline__ float bflo(unsigned u) { return __uint_as_float(u << 16); }
__device__ __forceinline__ float bfhi(unsigned u) { return __uint_as_float(u & 0xFFFF0000u); }

// ---------------------------------------------------------------------------
// one-time: W [k][col] f32 -> Wt [col][k] bf16 (two matrices) + bucket cursor init
__global__ __launch_bounds__(256)
void conv_w_kernel(const float* __restrict__ W0, const float* __restrict__ W1,
                   unsigned short* __restrict__ Wt0, unsigned short* __restrict__ Wt1,
                   int* __restrict__ bcur_e, int* __restrict__ bcur_v, int e_cap, int v_cap)
{
    int idx = blockIdx.x * 256 + threadIdx.x;
    int k = idx >> 7, c = idx & 127;
    Wt0[c * 128 + k] = bf16r(W0[idx]);
    Wt1[c * 128 + k] = bf16r(W1[idx]);
    if (blockIdx.x == 0) {
        bcur_e[threadIdx.x] = threadIdx.x * e_cap;
        bcur_v[threadIdx.x] = threadIdx.x * v_cap;
    }
}

// ---------------------------------------------------------------------------
// fused partition: both sides in one pass over the incidence list.
// LDS-staged bucket binning into fixed-capacity tmp regions.
__global__ __launch_bounds__(256)
void part2_kernel(const int* __restrict__ eidx, const int* __restrict__ vidx,
                  const float* __restrict__ vrw, const float* __restrict__ erw,
                  int* __restrict__ bcur_e, int* __restrict__ bcur_v,
                  int2* __restrict__ tmp_e, int2* __restrict__ tmp_v,
                  int M, int e_shift, int v_shift, int e_bk, int v_bk)
{
    __shared__ int lcnt_e[MAXB], lbase_e[MAXB], lcnt_v[MAXB], lbase_v[MAXB];
    const int t = threadIdx.x;
    const int base = blockIdx.x * PART_ELEMS;
    const int end = min(base + PART_ELEMS, M);

    if (t < e_bk) lcnt_e[t] = 0;
    if (t < v_bk) lcnt_v[t] = 0;
    __syncthreads();
    for (int j = base + t; j < end; j += 256) {
        atomicAdd(&lcnt_e[eidx[j] >> e_shift], 1);
        atomicAdd(&lcnt_v[vidx[j] >> v_shift], 1);
    }
    __syncthreads();
    if (t < e_bk) { int c = lcnt_e[t]; lbase_e[t] = c ? atomicAdd(&bcur_e[t], c) : 0; lcnt_e[t] = 0; }
    if (t < v_bk) { int c = lcnt_v[t]; lbase_v[t] = c ? atomicAdd(&bcur_v[t], c) : 0; lcnt_v[t] = 0; }
    __syncthreads();
    for (int j = base + t; j < end; j += 256) {
        int ei = eidx[j], vi = vidx[j];
        int wqe = (int)(vrw[j] * 32767.0f + 0.5f); wqe = wqe < 32767 ? wqe : 32767;
        int wqv = (int)(erw[j] * 32767.0f + 0.5f); wqv = wqv < 32767 ? wqv : 32767;
        int be = ei >> e_shift;
        int pe = lbase_e[be] + atomicAdd(&lcnt_e[be], 1);
        tmp_e[pe] = make_int2(ei | (wqe << 17), vi);
        int bv = vi >> v_shift;
        int pv = lbase_v[bv] + atomicAdd(&lcnt_v[bv], 1);
        tmp_v[pv] = make_int2(vi | (wqv << 17), ei);
    }
}

// ---------------------------------------------------------------------------
// fine pass (both sides, one launch): one block per bucket. Self-computes its
// pack base from bcur via LDS scan; LDS histogram + scan over the bucket's row
// range; writes start[] slice; places records into pack (L2-window writes).
__global__ __launch_bounds__(256)
void fine2_kernel(const int2* __restrict__ tmp_e, const int* __restrict__ bcur_e,
                  int e_cap, int e_shift, int En, int e_bk,
                  int* __restrict__ e_start, unsigned* __restrict__ e_pack,
                  const int2* __restrict__ tmp_v, const int* __restrict__ bcur_v,
                  int v_cap, int v_shift, int Nn, int v_bk,
                  int* __restrict__ v_start, unsigned* __restrict__ v_pack, int M)
{
    __shared__ int lcnt[MAXW];
    __shared__ int lstart[MAXW];
    __shared__ int sdata[256];
    __shared__ int scnt[256];
    __shared__ int spbase;

    const int t = threadIdx.x;
    const int2* tmp; const int* bcur; int cap, shift, n, nb, b;
    int* start; unsigned* pack;
    if ((int)blockIdx.x < e_bk) {
        tmp = tmp_e; bcur = bcur_e; cap = e_cap; shift = e_shift; n = En; nb = e_bk;
        start = e_start; pack = e_pack; b = blockIdx.x;
    } else {
        tmp = tmp_v; bcur = bcur_v; cap = v_cap; shift = v_shift; n = Nn; nb = v_bk;
        start = v_start; pack = v_pack; b = blockIdx.x - e_bk;
    }

    // self-computed pack base: exclusive prefix of bucket counts up to b
    int cnt_t = (t < nb) ? (bcur[t] - t * cap) : 0;
    scnt[t] = cnt_t;
    __syncthreads();
    int xx = cnt_t;
    for (int off = 1; off < 256; off <<= 1) {
        int y = (t >= off) ? scnt[t - off] : 0;
        __syncthreads();
        xx += y;
        scnt[t] = xx;
        __syncthreads();
    }
    if (t == b) spbase = xx - cnt_t;
    if (b == nb - 1 && t == 0) start[n] = M;
    __syncthreads();
    const int pbase = spbase;

    const int d0 = b << shift;
    const int width = min(1 << shift, n - d0);
    const int tbase = b * cap;
    const int nrec = bcur[b] - tbase;

    lcnt[t] = 0; lcnt[t + 256] = 0;
    __syncthreads();
    for (int j = t; j < nrec; j += 256)
        atomicAdd(&lcnt[(tmp[tbase + j].x & 0x1FFFF) - d0], 1);
    __syncthreads();
    int a = lcnt[2 * t], bb = lcnt[2 * t + 1];
    int s = a + bb;
    sdata[t] = s;
    __syncthreads();
    int x = s;
    for (int off = 1; off < 256; off <<= 1) {
        int y = (t >= off) ? sdata[t - off] : 0;
        __syncthreads();
        x += y;
        sdata[t] = x;
        __syncthreads();
    }
    int ex = x - s;
    lstart[2 * t] = ex;
    lstart[2 * t + 1] = ex + a;
    lcnt[2 * t] = 0; lcnt[2 * t + 1] = 0;   // reuse as cursors
    __syncthreads();
    for (int i = t; i < width; i += 256)
        start[d0 + i] = pbase + lstart[i];
    for (int j = t; j < nrec; j += 256) {
        int2 r = tmp[tbase + j];
        int di = (r.x & 0x1FFFF) - d0;
        int pos = pbase + lstart[di] + atomicAdd(&lcnt[di], 1);
        pack[pos] = (unsigned)r.y | (((unsigned)r.x >> 17) << 17);
    }
}

// ---------------------------------------------------------------------------
// MFMA GEMM: outb(bf16 u32-pairs) = epilogue(A @ W + bias)
template<bool V2E>
__global__ __launch_bounds__(256)
void gemm_mfma_kernel(const float* __restrict__ A, const unsigned short* __restrict__ Wtg,
                      const float* __restrict__ bias, const float* __restrict__ rowwt,
                      unsigned* __restrict__ outb, int nrows, float scale)
{
    __shared__ unsigned short Wt[128 * WT_LD];
    __shared__ unsigned short At[64 * WT_LD];

    const int t = threadIdx.x;
    const int row0 = blockIdx.x * 64;

    {
        int r = t >> 1, h = t & 1;
        const uint4* src = reinterpret_cast<const uint4*>(Wtg + r * 128 + h * 64);
        uint4* dst = reinterpret_cast<uint4*>(&Wt[r * WT_LD + h * 64]);
        #pragma unroll
        for (int i = 0; i < 8; ++i) dst[i] = src[i];
    }
    {
        int r = t >> 2, q = t & 3;
        int grow = row0 + r;
        uint4 o[4];
        if (grow < nrows) {
            const float4* src = reinterpret_cast<const float4*>(A + (size_t)grow * DD + q * 32);
            #pragma unroll
            for (int i = 0; i < 4; ++i) {
                float4 f0 = src[2 * i];
                float4 f1 = src[2 * i + 1];
                o[i].x = bf16pk(f0.x, f0.y);
                o[i].y = bf16pk(f0.z, f0.w);
                o[i].z = bf16pk(f1.x, f1.y);
                o[i].w = bf16pk(f1.z, f1.w);
            }
        } else {
            #pragma unroll
            for (int i = 0; i < 4; ++i) o[i] = make_uint4(0, 0, 0, 0);
        }
        uint4* dst = reinterpret_cast<uint4*>(&At[r * WT_LD + q * 32]);
        #pragma unroll
        for (int i = 0; i < 4; ++i) dst[i] = o[i];
    }
    __syncthreads();

    const int w  = t >> 6;
    const int l  = t & 63;
    const int lr = l & 15;
    const int lk = (l >> 4) * 8;

    f32x4 acc[8];
    #pragma unroll
    for (int i = 0; i < 8; ++i) acc[i] = 0.0f;

    const int arow = w * 16 + lr;
    #pragma unroll
    for (int ks = 0; ks < 4; ++ks) {
        bf16x8 af = *reinterpret_cast<const bf16x8*>(&At[arow * WT_LD + lk + ks * 32]);
        #pragma unroll
        for (int ct = 0; ct < 8; ++ct) {
            bf16x8 bfr = *reinterpret_cast<const bf16x8*>(&Wt[(ct * 16 + lr) * WT_LD + lk + ks * 32]);
            acc[ct] = __builtin_amdgcn_mfma_f32_16x16x32_bf16(af, bfr, acc[ct], 0, 0, 0);
        }
    }

    float bcol[8];
    #pragma unroll
    for (int ct = 0; ct < 8; ++ct) bcol[ct] = bias[ct * 16 + lr];
    #pragma unroll
    for (int r = 0; r < 4; ++r) {
        int rl = w * 16 + (l >> 4) * 4 + r;
        int grow = row0 + rl;
        float rw = scale;
        if (V2E) rw = (grow < nrows) ? rowwt[grow] : 0.f;
        #pragma unroll
        for (int ct = 0; ct < 8; ++ct) {
            float val = fmaxf(acc[ct][r] + bcol[ct], 0.f) * rw;
            At[rl * WT_LD + ct * 16 + lr] = bf16r(val);
        }
    }
    {
        int r = t >> 2, part = t & 3;
        int grow = row0 + r;
        if (grow < nrows) {
            const uint4* src = reinterpret_cast<const uint4*>(&At[r * WT_LD + part * 32]);
            uint4* dst = reinterpret_cast<uint4*>(outb + (size_t)grow * 64 + part * 16);
            dst[0] = src[0]; dst[1] = src[1]; dst[2] = src[2]; dst[3] = src[3];
        }
    }
}

// ---------------------------------------------------------------------------
// e-aggregation, half-wave paired gathers: lanes 0-31 take incidence j,
// lanes 32-63 take j+1; each lane loads uint2 (4 bf16 cols). Final combine
// via shfl_xor(32). One wave per edge row.
__global__ __launch_bounds__(256)
void e_agg_kernel(const float* __restrict__ e, const unsigned* __restrict__ vwb,
                  const int* __restrict__ start, const unsigned* __restrict__ pack,
                  const float* __restrict__ ers, float* __restrict__ eout, int E)
{
    int row = blockIdx.x * 4 + (threadIdx.x >> 6);
    if (row >= E) return;
    int lane = threadIdx.x & 63;
    int half = lane >> 5;
    int sl = lane & 31;
    int s = start[row], t = start[row + 1];

    float a0 = 0.f, a1 = 0.f, a2 = 0.f, a3 = 0.f;
    float b0 = 0.f, b1 = 0.f, b2 = 0.f, b3 = 0.f;
    float c0 = 0.f, c1 = 0.f, c2 = 0.f, c3 = 0.f;
    float d0 = 0.f, d1 = 0.f, d2 = 0.f, d3 = 0.f;

    int j = s;
    for (; j + 8 <= t; j += 8) {
        unsigned pw0 = pack[j + half];
        unsigned pw1 = pack[j + 2 + half];
        unsigned pw2 = pack[j + 4 + half];
        unsigned pw3 = pack[j + 6 + half];
        uint2 u0 = *reinterpret_cast<const uint2*>(&vwb[(size_t)(pw0 & 0x1FFFFu) * 64 + sl * 2]);
        uint2 u1 = *reinterpret_cast<const uint2*>(&vwb[(size_t)(pw1 & 0x1FFFFu) * 64 + sl * 2]);
        uint2 u2 = *reinterpret_cast<const uint2*>(&vwb[(size_t)(pw2 & 0x1FFFFu) * 64 + sl * 2]);
        uint2 u3 = *reinterpret_cast<const uint2*>(&vwb[(size_t)(pw3 & 0x1FFFFu) * 64 + sl * 2]);
        float w0 = (float)(pw0 >> 17) * (1.0f / 32767.0f);
        float w1 = (float)(pw1 >> 17) * (1.0f / 32767.0f);
        float w2 = (float)(pw2 >> 17) * (1.0f / 32767.0f);
        float w3 = (float)(pw3 >> 17) * (1.0f / 32767.0f);
        a0 = fmaf(bflo(u0.x), w0, a0); a1 = fmaf(bfhi(u0.x), w0, a1);
        a2 = fmaf(bflo(u0.y), w0, a2); a3 = fmaf(bfhi(u0.y), w0, a3);
        b0 = fmaf(bflo(u1.x), w1, b0); b1 = fmaf(bfhi(u1.x), w1, b1);
        b2 = fmaf(bflo(u1.y), w1, b2); b3 = fmaf(bfhi(u1.y), w1, b3);
        c0 = fmaf(bflo(u2.x), w2, c0); c1 = fmaf(bfhi(u2.x), w2, c1);
        c2 = fmaf(bflo(u2.y), w2, c2); c3 = fmaf(bfhi(u2.y), w2, c3);
        d0 = fmaf(bflo(u3.x), w3, d0); d1 = fmaf(bfhi(u3.x), w3, d1);
        d2 = fmaf(bflo(u3.y), w3, d2); d3 = fmaf(bfhi(u3.y), w3, d3);
    }
    for (; j < t; j += 2) {
        int jj = j + half;
        if (jj < t) {
            unsigned pw = pack[jj];
            float wm = (float)(pw >> 17) * (1.0f / 32767.0f);
            uint2 u = *reinterpret_cast<const uint2*>(&vwb[(size_t)(pw & 0x1FFFFu) * 64 + sl * 2]);
            a0 = fmaf(bflo(u.x), wm, a0); a1 = fmaf(bfhi(u.x), wm, a1);
            a2 = fmaf(bflo(u.y), wm, a2); a3 = fmaf(bfhi(u.y), wm, a3);
        }
    }
    float s0 = (a0 + b0) + (c0 + d0);
    float s1 = (a1 + b1) + (c1 + d1);
    float s2 = (a2 + b2) + (c2 + d2);
    float s3 = (a3 + b3) + (c3 + d3);
    s0 += __shfl_xor(s0, 32, 64);
    s1 += __shfl_xor(s1, 32, 64);
    s2 += __shfl_xor(s2, 32, 64);
    s3 += __shfl_xor(s3, 32, 64);
    if (half == 0) {
        float rs = 1.0f / ers[row];
        float4 er = *reinterpret_cast<const float4*>(&e[(size_t)row * DD + sl * 4]);
        float4 o = make_float4((er.x + s0) * rs, (er.y + s1) * rs,
                               (er.z + s2) * rs, (er.w + s3) * rs);
        *reinterpret_cast<float4*>(&eout[(size_t)row * DD + sl * 4]) = o;
    }
}

// ---------------------------------------------------------------------------
// v-aggregation, same half-wave structure.
__global__ __launch_bounds__(256)
void v_agg_kernel(const float* __restrict__ v, const unsigned* __restrict__ evb,
                  const int* __restrict__ start, const unsigned* __restrict__ pack,
                  const float* __restrict__ vrs, const float* __restrict__ vweight,
                  float* __restrict__ vout, int N)
{
    int row = blockIdx.x * 4 + (threadIdx.x >> 6);
    if (row >= N) return;
    int lane = threadIdx.x & 63;
    int half = lane >> 5;
    int sl = lane & 31;
    int s = start[row], t = start[row + 1];

    float a0 = 0.f, a1 = 0.f, a2 = 0.f, a3 = 0.f;
    float b0 = 0.f, b1 = 0.f, b2 = 0.f, b3 = 0.f;
    float c0 = 0.f, c1 = 0.f, c2 = 0.f, c3 = 0.f;
    float d0 = 0.f, d1 = 0.f, d2 = 0.f, d3 = 0.f;

    int j = s;
    for (; j + 8 <= t; j += 8) {
        unsigned pw0 = pack[j + half];
        unsigned pw1 = pack[j + 2 + half];
        unsigned pw2 = pack[j + 4 + half];
        unsigned pw3 = pack[j + 6 + half];
        uint2 u0 = *reinterpret_cast<const uint2*>(&evb[(size_t)(pw0 & 0x1FFFFu) * 64 + sl * 2]);
        uint2 u1 = *reinterpret_cast<const uint2*>(&evb[(size_t)(pw1 & 0x1FFFFu) * 64 + sl * 2]);
        uint2 u2 = *reinterpret_cast<const uint2*>(&evb[(size_t)(pw2 & 0x1FFFFu) * 64 + sl * 2]);
        uint2 u3 = *reinterpret_cast<const uint2*>(&evb[(size_t)(pw3 & 0x1FFFFu) * 64 + sl * 2]);
        float w0 = (float)(pw0 >> 17) * (1.0f / 32767.0f);
        float w1 = (float)(pw1 >> 17) * (1.0f / 32767.0f);
        float w2 = (float)(pw2 >> 17) * (1.0f / 32767.0f);
        float w3 = (float)(pw3 >> 17) * (1.0f / 32767.0f);
        a0 = fmaf(bflo(u0.x), w0, a0); a1 = fmaf(bfhi(u0.x), w0, a1);
        a2 = fmaf(bflo(u0.y), w0, a2); a3 = fmaf(bfhi(u0.y), w0, a3);
        b0 = fmaf(bflo(u1.x), w1, b0); b1 = fmaf(bfhi(u1.x), w1, b1);
        b2 = fmaf(bflo(u1.y), w1, b2); b3 = fmaf(bfhi(u1.y), w1, b3);
        c0 = fmaf(bflo(u2.x), w2, c0); c1 = fmaf(bfhi(u2.x), w2, c1);
        c2 = fmaf(bflo(u2.y), w2, c2); c3 = fmaf(bfhi(u2.y), w2, c3);
        d0 = fmaf(bflo(u3.x), w3, d0); d1 = fmaf(bfhi(u3.x), w3, d1);
        d2 = fmaf(bflo(u3.y), w3, d2); d3 = fmaf(bfhi(u3.y), w3, d3);
    }
    for (; j < t; j += 2) {
        int jj = j + half;
        if (jj < t) {
            unsigned pw = pack[jj];
            float wm = (float)(pw >> 17) * (1.0f / 32767.0f);
            uint2 u = *reinterpret_cast<const uint2*>(&evb[(size_t)(pw & 0x1FFFFu) * 64 + sl * 2]);
            a0 = fmaf(bflo(u.x), wm, a0); a1 = fmaf(bfhi(u.x), wm, a1);
            a2 = fmaf(bflo(u.y), wm, a2); a3 = fmaf(bfhi(u.y), wm, a3);
        }
    }
    float s0 = (a0 + b0) + (c0 + d0);
    float s1 = (a1 + b1) + (c1 + d1);
    float s2 = (a2 + b2) + (c2 + d2);
    float s3 = (a3 + b3) + (c3 + d3);
    s0 += __shfl_xor(s0, 32, 64);
    s1 += __shfl_xor(s1, 32, 64);
    s2 += __shfl_xor(s2, 32, 64);
    s3 += __shfl_xor(s3, 32, 64);
    if (half == 0) {
        float rs = 1.0f / vrs[row];
        float wt = vweight[row] * 4.0f;
        float4 vr = *reinterpret_cast<const float4*>(&v[(size_t)row * DD + sl * 4]);
        float4 o = make_float4((vr.x * wt + s0) * rs, (vr.y * wt + s1) * rs,
                               (vr.z * wt + s2) * rs, (vr.w * wt + s3) * rs);
        *reinterpret_cast<float4*>(&vout[(size_t)row * DD + sl * 4]) = o;
    }
}

// ---------------------------------------------------------------------------
extern "C" void kernel_launch(void* const* d_in, const int* in_sizes, int n_in,
                              void* d_out, int out_size, void* d_ws, size_t ws_size,
                              hipStream_t stream)
{
    const float* v       = (const float*)d_in[0];
    const float* e       = (const float*)d_in[1];
    const int*   vidx    = (const int*)d_in[2];
    const int*   eidx    = (const int*)d_in[3];
    const float* vrw     = (const float*)d_in[4];
    const float* erw     = (const float*)d_in[5];
    const float* vrs     = (const float*)d_in[6];
    const float* ers     = (const float*)d_in[7];
    const float* Wv2e    = (const float*)d_in[8];
    const float* We2v    = (const float*)d_in[9];
    const float* bv      = (const float*)d_in[10];
    const float* be      = (const float*)d_in[11];
    const float* vweight = (const float*)d_in[12];

    const int N = in_sizes[0] / DD;
    const int E = in_sizes[1] / DD;
    const int M = in_sizes[2];

    float* vout = (float*)d_out;
    float* eout = vout + (size_t)N * DD;

    // bucket geometry
    auto calc_shift = [](int n) {
        int s = 0;
        while (((n + (1 << s) - 1) >> s) > MAXB) ++s;
        return s;
    };
    const int e_shift = calc_shift(E);
    const int v_shift = calc_shift(N);
    const int e_bk = (E + (1 << e_shift) - 1) >> e_shift;
    const int v_bk = (N + (1 << v_shift) - 1) >> v_shift;
    const int e_cap = ((M / e_bk) * 3) / 2 + 256;
    const int v_cap = ((M / v_bk) * 3) / 2 + 256;

    // workspace layout (evb aliases vwb)
    char* wsb = (char*)d_ws;
    size_t off = 0;
    auto alloc = [&](size_t bytes) { char* p = wsb + off; off += (bytes + 255) & ~(size_t)255; return p; };
    unsigned* vwb   = (unsigned*)alloc((size_t)N * 64 * sizeof(unsigned));  // 25.6 MB
    unsigned* evb   = vwb;                                                  // alias
    int*   e_start = (int*)alloc((size_t)(E + 1) * sizeof(int));
    int*   v_start = (int*)alloc((size_t)(N + 1) * sizeof(int));
    int*   bcur_e  = (int*)alloc(MAXB * sizeof(int));
    int*   bcur_v  = (int*)alloc(MAXB * sizeof(int));
    unsigned short* Wt0 = (unsigned short*)alloc(DD * DD * sizeof(unsigned short));
    unsigned short* Wt1 = (unsigned short*)alloc(DD * DD * sizeof(unsigned short));
    unsigned* e_pack = (unsigned*)alloc((size_t)M * sizeof(unsigned));      // 4 MB
    unsigned* v_pack = (unsigned*)alloc((size_t)M * sizeof(unsigned));      // 4 MB
    int2*  tmp_e   = (int2*)alloc((size_t)e_bk * e_cap * sizeof(int2));     // ~12.4 MB
    int2*  tmp_v   = (int2*)alloc((size_t)v_bk * v_cap * sizeof(int2));     // ~12.4 MB

    const int pblk = (M + PART_ELEMS - 1) / PART_ELEMS;

    // 1. W convert + bucket cursor init
    conv_w_kernel<<<64, 256, 0, stream>>>(Wv2e, We2v, Wt0, Wt1, bcur_e, bcur_v, e_cap, v_cap);
    // 2. fused both-sides partition
    part2_kernel<<<pblk, 256, 0, stream>>>(eidx, vidx, vrw, erw, bcur_e, bcur_v,
                                           tmp_e, tmp_v, M, e_shift, v_shift, e_bk, v_bk);
    // 3. fused both-sides fine pass (CSR start[] + pack[])
    fine2_kernel<<<e_bk + v_bk, 256, 0, stream>>>(tmp_e, bcur_e, e_cap, e_shift, E, e_bk, e_start, e_pack,
                                                  tmp_v, bcur_v, v_cap, v_shift, N, v_bk, v_start, v_pack, M);
    // 4-7. compute chain
    gemm_mfma_kernel<true><<<(N + 63) / 64, 256, 0, stream>>>(v, Wt0, bv, vweight, vwb, N, 1.0f);
    e_agg_kernel<<<(E + 3) / 4, 256, 0, stream>>>(e, vwb, e_start, e_pack, ers, eout, E);
    gemm_mfma_kernel<false><<<(E + 63) / 64, 256, 0, stream>>>(eout, Wt1, be, nullptr, evb, E, 1.0f / 3.0f);
    v_agg_kernel<<<(N + 3) / 4, 256, 0, stream>>>(v, evb, v_start, v_pack, vrs, vweight, vout, N);
}

// Round 12
// 181.347 us; speedup vs baseline: 2.4711x; 1.0554x over previous
//
#include <hip/hip_runtime.h>
#include <cstddef>

#define DD 128
#define PART_ELEMS 4096   // elements per partition block (256 thr x 16)
#define MAXB 256          // max destination-range buckets
#define MAXW 512          // max rows per bucket (LDS counter width)
#define WT_LD 136         // padded bf16 leading dim

typedef __attribute__((ext_vector_type(8))) short bf16x8;
typedef __attribute__((ext_vector_type(4))) float f32x4;

__device__ __forceinline__ unsigned bf16pk(float x, float y) {
    unsigned a = __float_as_uint(x);
    unsigned b = __float_as_uint(y);
    a = (a + 0x7FFFu + ((a >> 16) & 1u)) >> 16;
    b = (b + 0x7FFFu + ((b >> 16) & 1u)) >> 16;
    return a | (b << 16);
}
__device__ __forceinline__ unsigned short bf16r(float x) {
    unsigned u = __float_as_uint(x);
    return (unsigned short)((u + 0x7FFFu + ((u >> 16) & 1u)) >> 16);
}
__device__ __forceinline__ float bflo(unsigned u) { return __uint_as_float(u << 16); }
__device__ __forceinline__ float bfhi(unsigned u) { return __uint_as_float(u & 0xFFFF0000u); }

// ---------------------------------------------------------------------------
// one-time: W [k][col] f32 -> Wt [col][k] bf16 (two matrices) + bucket cursor init
__global__ __launch_bounds__(256)
void conv_w_kernel(const float* __restrict__ W0, const float* __restrict__ W1,
                   unsigned short* __restrict__ Wt0, unsigned short* __restrict__ Wt1,
                   int* __restrict__ bcur_e, int* __restrict__ bcur_v, int e_cap, int v_cap)
{
    int idx = blockIdx.x * 256 + threadIdx.x;
    int k = idx >> 7, c = idx & 127;
    Wt0[c * 128 + k] = bf16r(W0[idx]);
    Wt1[c * 128 + k] = bf16r(W1[idx]);
    if (blockIdx.x == 0) {
        bcur_e[threadIdx.x] = threadIdx.x * e_cap;
        bcur_v[threadIdx.x] = threadIdx.x * v_cap;
    }
}

// ---------------------------------------------------------------------------
// fused partition: both sides in one pass over the incidence list.
__global__ __launch_bounds__(256)
void part2_kernel(const int* __restrict__ eidx, const int* __restrict__ vidx,
                  const float* __restrict__ vrw, const float* __restrict__ erw,
                  int* __restrict__ bcur_e, int* __restrict__ bcur_v,
                  int2* __restrict__ tmp_e, int2* __restrict__ tmp_v,
                  int M, int e_shift, int v_shift, int e_bk, int v_bk)
{
    __shared__ int lcnt_e[MAXB], lbase_e[MAXB], lcnt_v[MAXB], lbase_v[MAXB];
    const int t = threadIdx.x;
    const int base = blockIdx.x * PART_ELEMS;
    const int end = min(base + PART_ELEMS, M);

    if (t < e_bk) lcnt_e[t] = 0;
    if (t < v_bk) lcnt_v[t] = 0;
    __syncthreads();
    for (int j = base + t; j < end; j += 256) {
        atomicAdd(&lcnt_e[eidx[j] >> e_shift], 1);
        atomicAdd(&lcnt_v[vidx[j] >> v_shift], 1);
    }
    __syncthreads();
    if (t < e_bk) { int c = lcnt_e[t]; lbase_e[t] = c ? atomicAdd(&bcur_e[t], c) : 0; lcnt_e[t] = 0; }
    if (t < v_bk) { int c = lcnt_v[t]; lbase_v[t] = c ? atomicAdd(&bcur_v[t], c) : 0; lcnt_v[t] = 0; }
    __syncthreads();
    for (int j = base + t; j < end; j += 256) {
        int ei = eidx[j], vi = vidx[j];
        int wqe = (int)(vrw[j] * 32767.0f + 0.5f); wqe = wqe < 32767 ? wqe : 32767;
        int wqv = (int)(erw[j] * 32767.0f + 0.5f); wqv = wqv < 32767 ? wqv : 32767;
        int be = ei >> e_shift;
        int pe = lbase_e[be] + atomicAdd(&lcnt_e[be], 1);
        tmp_e[pe] = make_int2(ei | (wqe << 17), vi);
        int bv = vi >> v_shift;
        int pv = lbase_v[bv] + atomicAdd(&lcnt_v[bv], 1);
        tmp_v[pv] = make_int2(vi | (wqv << 17), ei);
    }
}

// ---------------------------------------------------------------------------
// device bodies so fine-pass and GEMM can share one fused launch
struct FineLds { int lcnt[MAXW]; int lstart[MAXW]; int sdata[256]; int scnt[256]; int spbase; };
struct GemmLds { unsigned short Wt[128 * WT_LD]; unsigned short At[64 * WT_LD]; };

__device__ __forceinline__
void fine_body(int blk, FineLds& L,
               const int2* __restrict__ tmp_e, const int* __restrict__ bcur_e,
               int e_cap, int e_shift, int En, int e_bk,
               int* __restrict__ e_start, unsigned* __restrict__ e_pack,
               const int2* __restrict__ tmp_v, const int* __restrict__ bcur_v,
               int v_cap, int v_shift, int Nn, int v_bk,
               int* __restrict__ v_start, unsigned* __restrict__ v_pack, int M)
{
    const int t = threadIdx.x;
    const int2* tmp; const int* bcur; int cap, shift, n, nb, b;
    int* start; unsigned* pack;
    if (blk < e_bk) {
        tmp = tmp_e; bcur = bcur_e; cap = e_cap; shift = e_shift; n = En; nb = e_bk;
        start = e_start; pack = e_pack; b = blk;
    } else {
        tmp = tmp_v; bcur = bcur_v; cap = v_cap; shift = v_shift; n = Nn; nb = v_bk;
        start = v_start; pack = v_pack; b = blk - e_bk;
    }

    // self-computed pack base: exclusive prefix of bucket counts up to b
    int cnt_t = (t < nb) ? (bcur[t] - t * cap) : 0;
    L.scnt[t] = cnt_t;
    __syncthreads();
    int xx = cnt_t;
    for (int off = 1; off < 256; off <<= 1) {
        int y = (t >= off) ? L.scnt[t - off] : 0;
        __syncthreads();
        xx += y;
        L.scnt[t] = xx;
        __syncthreads();
    }
    if (t == b) L.spbase = xx - cnt_t;
    if (b == nb - 1 && t == 0) start[n] = M;
    __syncthreads();
    const int pbase = L.spbase;

    const int d0 = b << shift;
    const int width = min(1 << shift, n - d0);
    const int tbase = b * cap;
    const int nrec = bcur[b] - tbase;

    L.lcnt[t] = 0; L.lcnt[t + 256] = 0;
    __syncthreads();
    for (int j = t; j < nrec; j += 256)
        atomicAdd(&L.lcnt[(tmp[tbase + j].x & 0x1FFFF) - d0], 1);
    __syncthreads();
    int a = L.lcnt[2 * t], bb = L.lcnt[2 * t + 1];
    int s = a + bb;
    L.sdata[t] = s;
    __syncthreads();
    int x = s;
    for (int off = 1; off < 256; off <<= 1) {
        int y = (t >= off) ? L.sdata[t - off] : 0;
        __syncthreads();
        x += y;
        L.sdata[t] = x;
        __syncthreads();
    }
    int ex = x - s;
    L.lstart[2 * t] = ex;
    L.lstart[2 * t + 1] = ex + a;
    L.lcnt[2 * t] = 0; L.lcnt[2 * t + 1] = 0;   // reuse as cursors
    __syncthreads();
    for (int i = t; i < width; i += 256)
        start[d0 + i] = pbase + L.lstart[i];
    for (int j = t; j < nrec; j += 256) {
        int2 r = tmp[tbase + j];
        int di = (r.x & 0x1FFFF) - d0;
        int pos = pbase + L.lstart[di] + atomicAdd(&L.lcnt[di], 1);
        pack[pos] = (unsigned)r.y | (((unsigned)r.x >> 17) << 17);
    }
}

__device__ __forceinline__
void gemm_body(int blk, GemmLds& L, const float* __restrict__ A,
               const unsigned short* __restrict__ Wtg, const float* __restrict__ bias,
               const float* __restrict__ rowwt, unsigned* __restrict__ outb,
               int nrows, float scale, bool v2e)
{
    const int t = threadIdx.x;
    const int row0 = blk * 64;

    {
        int r = t >> 1, h = t & 1;
        const uint4* src = reinterpret_cast<const uint4*>(Wtg + r * 128 + h * 64);
        uint4* dst = reinterpret_cast<uint4*>(&L.Wt[r * WT_LD + h * 64]);
        #pragma unroll
        for (int i = 0; i < 8; ++i) dst[i] = src[i];
    }
    {
        int r = t >> 2, q = t & 3;
        int grow = row0 + r;
        uint4 o[4];
        if (grow < nrows) {
            const float4* src = reinterpret_cast<const float4*>(A + (size_t)grow * DD + q * 32);
            #pragma unroll
            for (int i = 0; i < 4; ++i) {
                float4 f0 = src[2 * i];
                float4 f1 = src[2 * i + 1];
                o[i].x = bf16pk(f0.x, f0.y);
                o[i].y = bf16pk(f0.z, f0.w);
                o[i].z = bf16pk(f1.x, f1.y);
                o[i].w = bf16pk(f1.z, f1.w);
            }
        } else {
            #pragma unroll
            for (int i = 0; i < 4; ++i) o[i] = make_uint4(0, 0, 0, 0);
        }
        uint4* dst = reinterpret_cast<uint4*>(&L.At[r * WT_LD + q * 32]);
        #pragma unroll
        for (int i = 0; i < 4; ++i) dst[i] = o[i];
    }
    __syncthreads();

    const int w  = t >> 6;
    const int l  = t & 63;
    const int lr = l & 15;
    const int lk = (l >> 4) * 8;

    f32x4 acc[8];
    #pragma unroll
    for (int i = 0; i < 8; ++i) acc[i] = 0.0f;

    const int arow = w * 16 + lr;
    #pragma unroll
    for (int ks = 0; ks < 4; ++ks) {
        bf16x8 af = *reinterpret_cast<const bf16x8*>(&L.At[arow * WT_LD + lk + ks * 32]);
        #pragma unroll
        for (int ct = 0; ct < 8; ++ct) {
            bf16x8 bfr = *reinterpret_cast<const bf16x8*>(&L.Wt[(ct * 16 + lr) * WT_LD + lk + ks * 32]);
            acc[ct] = __builtin_amdgcn_mfma_f32_16x16x32_bf16(af, bfr, acc[ct], 0, 0, 0);
        }
    }

    float bcol[8];
    #pragma unroll
    for (int ct = 0; ct < 8; ++ct) bcol[ct] = bias[ct * 16 + lr];
    #pragma unroll
    for (int r = 0; r < 4; ++r) {
        int rl = w * 16 + (l >> 4) * 4 + r;
        int grow = row0 + rl;
        float rw = scale;
        if (v2e) rw = (grow < nrows) ? rowwt[grow] : 0.f;
        #pragma unroll
        for (int ct = 0; ct < 8; ++ct) {
            float val = fmaxf(acc[ct][r] + bcol[ct], 0.f) * rw;
            L.At[rl * WT_LD + ct * 16 + lr] = bf16r(val);
        }
    }
    {
        int r = t >> 2, part = t & 3;
        int grow = row0 + r;
        if (grow < nrows) {
            const uint4* src = reinterpret_cast<const uint4*>(&L.At[r * WT_LD + part * 32]);
            uint4* dst = reinterpret_cast<uint4*>(outb + (size_t)grow * 64 + part * 16);
            dst[0] = src[0]; dst[1] = src[1]; dst[2] = src[2]; dst[3] = src[3];
        }
    }
}

// ---------------------------------------------------------------------------
// fused launch: blocks [0, e_bk+v_bk) do the fine pass; the rest do the v2e GEMM
__global__ __launch_bounds__(256)
void fused_fine_gemm_kernel(const int2* __restrict__ tmp_e, const int* __restrict__ bcur_e,
                            int e_cap, int e_shift, int En, int e_bk,
                            int* __restrict__ e_start, unsigned* __restrict__ e_pack,
                            const int2* __restrict__ tmp_v, const int* __restrict__ bcur_v,
                            int v_cap, int v_shift, int Nn, int v_bk,
                            int* __restrict__ v_start, unsigned* __restrict__ v_pack, int M,
                            const float* __restrict__ v, const unsigned short* __restrict__ Wt0,
                            const float* __restrict__ bv, const float* __restrict__ vweight,
                            unsigned* __restrict__ vwb)
{
    __shared__ union SM { FineLds f; GemmLds g; } sm;
    const int nfine = e_bk + v_bk;
    if ((int)blockIdx.x < nfine) {
        fine_body(blockIdx.x, sm.f, tmp_e, bcur_e, e_cap, e_shift, En, e_bk, e_start, e_pack,
                  tmp_v, bcur_v, v_cap, v_shift, Nn, v_bk, v_start, v_pack, M);
    } else {
        gemm_body(blockIdx.x - nfine, sm.g, v, Wt0, bv, vweight, vwb, Nn, 1.0f, true);
    }
}

// standalone GEMM for the e2v side
__global__ __launch_bounds__(256)
void gemm_mfma_kernel(const float* __restrict__ A, const unsigned short* __restrict__ Wtg,
                      const float* __restrict__ bias, unsigned* __restrict__ outb,
                      int nrows, float scale)
{
    __shared__ GemmLds sm;
    gemm_body(blockIdx.x, sm, A, Wtg, bias, nullptr, outb, nrows, scale, false);
}

// ---------------------------------------------------------------------------
// e-aggregation, quarter-wave gathers: lane group (lane>>4) takes incidence
// j+qw; each lane loads uint4 (8 bf16 cols). Combine via shfl_xor(16,32).
__global__ __launch_bounds__(256)
void e_agg_kernel(const float* __restrict__ e, const unsigned* __restrict__ vwb,
                  const int* __restrict__ start, const unsigned* __restrict__ pack,
                  const float* __restrict__ ers, float* __restrict__ eout, int E)
{
    int row = blockIdx.x * 4 + (threadIdx.x >> 6);
    if (row >= E) return;
    int lane = threadIdx.x & 63;
    int qw = lane >> 4;
    int ql = lane & 15;
    int s = start[row], t = start[row + 1];

    float a0=0.f,a1=0.f,a2=0.f,a3=0.f,a4=0.f,a5=0.f,a6=0.f,a7=0.f;
    float b0=0.f,b1=0.f,b2=0.f,b3=0.f,b4=0.f,b5=0.f,b6=0.f,b7=0.f;

    int j = s;
    for (; j + 8 <= t; j += 8) {
        unsigned pw0 = pack[j + qw];
        unsigned pw1 = pack[j + 4 + qw];
        uint4 u0 = *reinterpret_cast<const uint4*>(&vwb[(size_t)(pw0 & 0x1FFFFu) * 64 + ql * 4]);
        uint4 u1 = *reinterpret_cast<const uint4*>(&vwb[(size_t)(pw1 & 0x1FFFFu) * 64 + ql * 4]);
        float w0 = (float)(pw0 >> 17) * (1.0f / 32767.0f);
        float w1 = (float)(pw1 >> 17) * (1.0f / 32767.0f);
        a0 = fmaf(bflo(u0.x), w0, a0); a1 = fmaf(bfhi(u0.x), w0, a1);
        a2 = fmaf(bflo(u0.y), w0, a2); a3 = fmaf(bfhi(u0.y), w0, a3);
        a4 = fmaf(bflo(u0.z), w0, a4); a5 = fmaf(bfhi(u0.z), w0, a5);
        a6 = fmaf(bflo(u0.w), w0, a6); a7 = fmaf(bfhi(u0.w), w0, a7);
        b0 = fmaf(bflo(u1.x), w1, b0); b1 = fmaf(bfhi(u1.x), w1, b1);
        b2 = fmaf(bflo(u1.y), w1, b2); b3 = fmaf(bfhi(u1.y), w1, b3);
        b4 = fmaf(bflo(u1.z), w1, b4); b5 = fmaf(bfhi(u1.z), w1, b5);
        b6 = fmaf(bflo(u1.w), w1, b6); b7 = fmaf(bfhi(u1.w), w1, b7);
    }
    for (; j < t; j += 4) {
        int jj = j + qw;
        if (jj < t) {
            unsigned pw = pack[jj];
            float wm = (float)(pw >> 17) * (1.0f / 32767.0f);
            uint4 u = *reinterpret_cast<const uint4*>(&vwb[(size_t)(pw & 0x1FFFFu) * 64 + ql * 4]);
            a0 = fmaf(bflo(u.x), wm, a0); a1 = fmaf(bfhi(u.x), wm, a1);
            a2 = fmaf(bflo(u.y), wm, a2); a3 = fmaf(bfhi(u.y), wm, a3);
            a4 = fmaf(bflo(u.z), wm, a4); a5 = fmaf(bfhi(u.z), wm, a5);
            a6 = fmaf(bflo(u.w), wm, a6); a7 = fmaf(bfhi(u.w), wm, a7);
        }
    }
    float r0 = a0 + b0, r1 = a1 + b1, r2 = a2 + b2, r3 = a3 + b3;
    float r4 = a4 + b4, r5 = a5 + b5, r6 = a6 + b6, r7 = a7 + b7;
    r0 += __shfl_xor(r0, 16, 64); r0 += __shfl_xor(r0, 32, 64);
    r1 += __shfl_xor(r1, 16, 64); r1 += __shfl_xor(r1, 32, 64);
    r2 += __shfl_xor(r2, 16, 64); r2 += __shfl_xor(r2, 32, 64);
    r3 += __shfl_xor(r3, 16, 64); r3 += __shfl_xor(r3, 32, 64);
    r4 += __shfl_xor(r4, 16, 64); r4 += __shfl_xor(r4, 32, 64);
    r5 += __shfl_xor(r5, 16, 64); r5 += __shfl_xor(r5, 32, 64);
    r6 += __shfl_xor(r6, 16, 64); r6 += __shfl_xor(r6, 32, 64);
    r7 += __shfl_xor(r7, 16, 64); r7 += __shfl_xor(r7, 32, 64);
    if (qw == 0) {
        float rs = 1.0f / ers[row];
        const float4* ep = reinterpret_cast<const float4*>(&e[(size_t)row * DD + ql * 8]);
        float4 e0 = ep[0], e1 = ep[1];
        float4 o0 = make_float4((e0.x + r0) * rs, (e0.y + r1) * rs, (e0.z + r2) * rs, (e0.w + r3) * rs);
        float4 o1 = make_float4((e1.x + r4) * rs, (e1.y + r5) * rs, (e1.z + r6) * rs, (e1.w + r7) * rs);
        float4* op = reinterpret_cast<float4*>(&eout[(size_t)row * DD + ql * 8]);
        op[0] = o0; op[1] = o1;
    }
}

// ---------------------------------------------------------------------------
// v-aggregation, same quarter-wave structure.
__global__ __launch_bounds__(256)
void v_agg_kernel(const float* __restrict__ v, const unsigned* __restrict__ evb,
                  const int* __restrict__ start, const unsigned* __restrict__ pack,
                  const float* __restrict__ vrs, const float* __restrict__ vweight,
                  float* __restrict__ vout, int N)
{
    int row = blockIdx.x * 4 + (threadIdx.x >> 6);
    if (row >= N) return;
    int lane = threadIdx.x & 63;
    int qw = lane >> 4;
    int ql = lane & 15;
    int s = start[row], t = start[row + 1];

    float a0=0.f,a1=0.f,a2=0.f,a3=0.f,a4=0.f,a5=0.f,a6=0.f,a7=0.f;
    float b0=0.f,b1=0.f,b2=0.f,b3=0.f,b4=0.f,b5=0.f,b6=0.f,b7=0.f;

    int j = s;
    for (; j + 8 <= t; j += 8) {
        unsigned pw0 = pack[j + qw];
        unsigned pw1 = pack[j + 4 + qw];
        uint4 u0 = *reinterpret_cast<const uint4*>(&evb[(size_t)(pw0 & 0x1FFFFu) * 64 + ql * 4]);
        uint4 u1 = *reinterpret_cast<const uint4*>(&evb[(size_t)(pw1 & 0x1FFFFu) * 64 + ql * 4]);
        float w0 = (float)(pw0 >> 17) * (1.0f / 32767.0f);
        float w1 = (float)(pw1 >> 17) * (1.0f / 32767.0f);
        a0 = fmaf(bflo(u0.x), w0, a0); a1 = fmaf(bfhi(u0.x), w0, a1);
        a2 = fmaf(bflo(u0.y), w0, a2); a3 = fmaf(bfhi(u0.y), w0, a3);
        a4 = fmaf(bflo(u0.z), w0, a4); a5 = fmaf(bfhi(u0.z), w0, a5);
        a6 = fmaf(bflo(u0.w), w0, a6); a7 = fmaf(bfhi(u0.w), w0, a7);
        b0 = fmaf(bflo(u1.x), w1, b0); b1 = fmaf(bfhi(u1.x), w1, b1);
        b2 = fmaf(bflo(u1.y), w1, b2); b3 = fmaf(bfhi(u1.y), w1, b3);
        b4 = fmaf(bflo(u1.z), w1, b4); b5 = fmaf(bfhi(u1.z), w1, b5);
        b6 = fmaf(bflo(u1.w), w1, b6); b7 = fmaf(bfhi(u1.w), w1, b7);
    }
    for (; j < t; j += 4) {
        int jj = j + qw;
        if (jj < t) {
            unsigned pw = pack[jj];
            float wm = (float)(pw >> 17) * (1.0f / 32767.0f);
            uint4 u = *reinterpret_cast<const uint4*>(&evb[(size_t)(pw & 0x1FFFFu) * 64 + ql * 4]);
            a0 = fmaf(bflo(u.x), wm, a0); a1 = fmaf(bfhi(u.x), wm, a1);
            a2 = fmaf(bflo(u.y), wm, a2); a3 = fmaf(bfhi(u.y), wm, a3);
            a4 = fmaf(bflo(u.z), wm, a4); a5 = fmaf(bfhi(u.z), wm, a5);
            a6 = fmaf(bflo(u.w), wm, a6); a7 = fmaf(bfhi(u.w), wm, a7);
        }
    }
    float r0 = a0 + b0, r1 = a1 + b1, r2 = a2 + b2, r3 = a3 + b3;
    float r4 = a4 + b4, r5 = a5 + b5, r6 = a6 + b6, r7 = a7 + b7;
    r0 += __shfl_xor(r0, 16, 64); r0 += __shfl_xor(r0, 32, 64);
    r1 += __shfl_xor(r1, 16, 64); r1 += __shfl_xor(r1, 32, 64);
    r2 += __shfl_xor(r2, 16, 64); r2 += __shfl_xor(r2, 32, 64);
    r3 += __shfl_xor(r3, 16, 64); r3 += __shfl_xor(r3, 32, 64);
    r4 += __shfl_xor(r4, 16, 64); r4 += __shfl_xor(r4, 32, 64);
    r5 += __shfl_xor(r5, 16, 64); r5 += __shfl_xor(r5, 32, 64);
    r6 += __shfl_xor(r6, 16, 64); r6 += __shfl_xor(r6, 32, 64);
    r7 += __shfl_xor(r7, 16, 64); r7 += __shfl_xor(r7, 32, 64);
    if (qw == 0) {
        float rs = 1.0f / vrs[row];
        float wt = vweight[row] * 4.0f;
        const float4* vp = reinterpret_cast<const float4*>(&v[(size_t)row * DD + ql * 8]);
        float4 v0 = vp[0], v1 = vp[1];
        float4 o0 = make_float4((v0.x * wt + r0) * rs, (v0.y * wt + r1) * rs,
                                (v0.z * wt + r2) * rs, (v0.w * wt + r3) * rs);
        float4 o1 = make_float4((v1.x * wt + r4) * rs, (v1.y * wt + r5) * rs,
                                (v1.z * wt + r6) * rs, (v1.w * wt + r7) * rs);
        float4* op = reinterpret_cast<float4*>(&vout[(size_t)row * DD + ql * 8]);
        op[0] = o0; op[1] = o1;
    }
}

// ---------------------------------------------------------------------------
extern "C" void kernel_launch(void* const* d_in, const int* in_sizes, int n_in,
                              void* d_out, int out_size, void* d_ws, size_t ws_size,
                              hipStream_t stream)
{
    const float* v       = (const float*)d_in[0];
    const float* e       = (const float*)d_in[1];
    const int*   vidx    = (const int*)d_in[2];
    const int*   eidx    = (const int*)d_in[3];
    const float* vrw     = (const float*)d_in[4];
    const float* erw     = (const float*)d_in[5];
    const float* vrs     = (const float*)d_in[6];
    const float* ers     = (const float*)d_in[7];
    const float* Wv2e    = (const float*)d_in[8];
    const float* We2v    = (const float*)d_in[9];
    const float* bv      = (const float*)d_in[10];
    const float* be      = (const float*)d_in[11];
    const float* vweight = (const float*)d_in[12];

    const int N = in_sizes[0] / DD;
    const int E = in_sizes[1] / DD;
    const int M = in_sizes[2];

    float* vout = (float*)d_out;
    float* eout = vout + (size_t)N * DD;

    // bucket geometry
    auto calc_shift = [](int n) {
        int s = 0;
        while (((n + (1 << s) - 1) >> s) > MAXB) ++s;
        return s;
    };
    const int e_shift = calc_shift(E);
    const int v_shift = calc_shift(N);
    const int e_bk = (E + (1 << e_shift) - 1) >> e_shift;
    const int v_bk = (N + (1 << v_shift) - 1) >> v_shift;
    const int e_cap = ((M / e_bk) * 3) / 2 + 256;
    const int v_cap = ((M / v_bk) * 3) / 2 + 256;

    // workspace layout (evb aliases vwb)
    char* wsb = (char*)d_ws;
    size_t off = 0;
    auto alloc = [&](size_t bytes) { char* p = wsb + off; off += (bytes + 255) & ~(size_t)255; return p; };
    unsigned* vwb   = (unsigned*)alloc((size_t)N * 64 * sizeof(unsigned));  // 25.6 MB
    unsigned* evb   = vwb;                                                  // alias
    int*   e_start = (int*)alloc((size_t)(E + 1) * sizeof(int));
    int*   v_start = (int*)alloc((size_t)(N + 1) * sizeof(int));
    int*   bcur_e  = (int*)alloc(MAXB * sizeof(int));
    int*   bcur_v  = (int*)alloc(MAXB * sizeof(int));
    unsigned short* Wt0 = (unsigned short*)alloc(DD * DD * sizeof(unsigned short));
    unsigned short* Wt1 = (unsigned short*)alloc(DD * DD * sizeof(unsigned short));
    unsigned* e_pack = (unsigned*)alloc((size_t)M * sizeof(unsigned));      // 4 MB
    unsigned* v_pack = (unsigned*)alloc((size_t)M * sizeof(unsigned));      // 4 MB
    int2*  tmp_e   = (int2*)alloc((size_t)e_bk * e_cap * sizeof(int2));     // ~12.4 MB
    int2*  tmp_v   = (int2*)alloc((size_t)v_bk * v_cap * sizeof(int2));     // ~12.4 MB

    const int pblk = (M + PART_ELEMS - 1) / PART_ELEMS;
    const int gblkN = (N + 63) / 64;

    // 1. W convert + bucket cursor init
    conv_w_kernel<<<64, 256, 0, stream>>>(Wv2e, We2v, Wt0, Wt1, bcur_e, bcur_v, e_cap, v_cap);
    // 2. fused both-sides partition
    part2_kernel<<<pblk, 256, 0, stream>>>(eidx, vidx, vrw, erw, bcur_e, bcur_v,
                                           tmp_e, tmp_v, M, e_shift, v_shift, e_bk, v_bk);
    // 3. fused fine pass + v2e GEMM (independent of each other)
    fused_fine_gemm_kernel<<<e_bk + v_bk + gblkN, 256, 0, stream>>>(
        tmp_e, bcur_e, e_cap, e_shift, E, e_bk, e_start, e_pack,
        tmp_v, bcur_v, v_cap, v_shift, N, v_bk, v_start, v_pack, M,
        v, Wt0, bv, vweight, vwb);
    // 4. e-aggregation
    e_agg_kernel<<<(E + 3) / 4, 256, 0, stream>>>(e, vwb, e_start, e_pack, ers, eout, E);
    // 5. e2v GEMM
    gemm_mfma_kernel<<<(E + 63) / 64, 256, 0, stream>>>(eout, Wt1, be, evb, E, 1.0f / 3.0f);
    // 6. v-aggregation
    v_agg_kernel<<<(N + 3) / 4, 256, 0, stream>>>(v, evb, v_start, v_pack, vrs, vweight, vout, N);
}